// Round 3
// baseline (810.999 us; speedup 1.0000x reference)
//
#include <hip/hip_runtime.h>
#include <math.h>

#define NEG_SLOPE 0.2f

__device__ __forceinline__ float lrelu(float x) { return x >= 0.f ? x : NEG_SLOPE * x; }

// ---------------------------------------------------------------------------
// Y[N x C] = X[N x 128] @ W[128 x C] + b     (C = 128 or 32)
// Register-tiled: 8 rows per thread (8 independent FMA chains), W in LDS.
// Per 4-k chunk: 4 LDS b32 reads (2-way bank alias = free) reused by 8 rows;
// x loads are wave-uniform float4 -> L1 broadcast.
// ---------------------------------------------------------------------------
template <int C>
__global__ __launch_bounds__(256) void xform_kernel(
    const float* __restrict__ X, const float* __restrict__ W,
    const float* __restrict__ b, float* __restrict__ Y, int n) {
  constexpr int RPT = 8;            // rows per thread
  constexpr int RS = 256 / C;       // row slots per block
  constexpr int RPP = RS * RPT;     // rows per pass
  __shared__ float Wl[128 * C];
  for (int i = threadIdx.x * 4; i < 128 * C; i += 256 * 4) {
    *(float4*)(Wl + i) = *(const float4*)(W + i);
  }
  __syncthreads();
  const int c = threadIdx.x % C;
  const int rsub = threadIdx.x / C;
  const int row0 = blockIdx.x * 64;
  const int rowEnd = min(row0 + 64, n);
  const float bc = b[c];
  for (int rbase = row0 + rsub * RPT; rbase < rowEnd; rbase += RPP) {
    const float* xr[RPT];
#pragma unroll
    for (int i = 0; i < RPT; i++) {
      int r = min(rbase + i, n - 1);
      xr[i] = X + (size_t)r * 128;
    }
    float acc[RPT];
#pragma unroll
    for (int i = 0; i < RPT; i++) acc[i] = bc;
#pragma unroll 4
    for (int k = 0; k < 128; k += 4) {
      const float w0 = Wl[(k + 0) * C + c];
      const float w1 = Wl[(k + 1) * C + c];
      const float w2 = Wl[(k + 2) * C + c];
      const float w3 = Wl[(k + 3) * C + c];
#pragma unroll
      for (int i = 0; i < RPT; i++) {
        float4 xv = *(const float4*)(xr[i] + k);
        acc[i] += xv.x * w0 + xv.y * w1 + xv.z * w2 + xv.w * w3;
      }
    }
#pragma unroll
    for (int i = 0; i < RPT; i++) {
      if (rbase + i < rowEnd) Y[(size_t)(rbase + i) * C + c] = acc[i];
    }
  }
}

// ---------------------------------------------------------------------------
// CSR build: histogram by dst, exclusive scan, scatter src into dst-order.
// Self-loops are NOT in the CSR; fused kernels add them inline.
// ---------------------------------------------------------------------------
__global__ __launch_bounds__(256) void hist_kernel(
    const int* __restrict__ ei, int* __restrict__ count, int N, int E) {
  int e = blockIdx.x * 256 + threadIdx.x;
  if (e >= E) return;
  int d = ei[E + e];
  d = min(max(d, 0), N - 1);
  atomicAdd(count + d, 1);
}

__global__ __launch_bounds__(1024) void scan_kernel(
    const int* __restrict__ count, int* __restrict__ row_ofs,
    int* __restrict__ wofs, int n) {
  __shared__ int partial[1024];
  const int tid = threadIdx.x;
  const int chunk = (n + 1023) / 1024;
  const int begin = min(tid * chunk, n);
  const int end = min(begin + chunk, n);
  int s = 0;
  for (int i = begin; i < end; i++) s += count[i];
  partial[tid] = s;
  __syncthreads();
  for (int off = 1; off < 1024; off <<= 1) {
    int t = (tid >= off) ? partial[tid - off] : 0;
    __syncthreads();
    partial[tid] += t;
    __syncthreads();
  }
  int running = partial[tid] - s;  // exclusive base of this chunk
  for (int i = begin; i < end; i++) {
    row_ofs[i] = running;
    wofs[i] = running;
    running += count[i];
  }
  if (tid == 1023) row_ofs[n] = partial[1023];
}

__global__ __launch_bounds__(256) void scatter_kernel(
    const int* __restrict__ ei, int* __restrict__ wofs,
    int* __restrict__ src_sorted, int N, int E) {
  int e = blockIdx.x * 256 + threadIdx.x;
  if (e >= E) return;
  int s = ei[e], d = ei[E + e];
  s = min(max(s, 0), N - 1);
  d = min(max(d, 0), N - 1);
  int pos = atomicAdd(wofs + d, 1);
  src_sorted[pos] = s;
}

// ---------------------------------------------------------------------------
// Layer-1 fused: per dst node (one wave), gather in-edges, accumulate
//   out = (sum_e ex_e * msg_e) / (sum_e ex_e);  then +bias, ELU.
// lane l covers channels 2l,2l+1; head h = lane/8.
// ---------------------------------------------------------------------------
__global__ __launch_bounds__(256) void gat1_fused(
    const int* __restrict__ row_ofs, const int* __restrict__ src_sorted,
    const float* __restrict__ xs, const float* __restrict__ xd,
    const float* __restrict__ att, const float* __restrict__ bias,
    float* __restrict__ h1, int N) {
  const int node = (int)((blockIdx.x * 256u + threadIdx.x) >> 6);
  const int lane = threadIdx.x & 63;
  if (node >= N) return;
  const float2 at = *(const float2*)(att + 2 * lane);
  const float2 xdv = *(const float2*)(xd + (size_t)node * 128 + 2 * lane);
  float2 acc = make_float2(0.f, 0.f);
  float den = 0.f;
  const int b = row_ofs[node], eend = row_ofs[node + 1];
  // self-loop (always appended by reference)
  {
    float2 m = *(const float2*)(xs + (size_t)node * 128 + 2 * lane);
    float p = lrelu(m.x + xdv.x) * at.x + lrelu(m.y + xdv.y) * at.y;
    p += __shfl_xor(p, 1);
    p += __shfl_xor(p, 2);
    p += __shfl_xor(p, 4);
    float ex = __expf(p);
    den += ex;
    acc.x += ex * m.x;
    acc.y += ex * m.y;
  }
  int sNext = (b < eend) ? src_sorted[b] : 0;
  for (int e = b; e < eend; e++) {
    const int s = sNext;
    sNext = (e + 1 < eend) ? src_sorted[e + 1] : 0;
    float2 m = *(const float2*)(xs + (size_t)s * 128 + 2 * lane);
    float p = lrelu(m.x + xdv.x) * at.x + lrelu(m.y + xdv.y) * at.y;
    p += __shfl_xor(p, 1);
    p += __shfl_xor(p, 2);
    p += __shfl_xor(p, 4);
    float ex = __expf(p);
    den += ex;
    acc.x += ex * m.x;
    acc.y += ex * m.y;
  }
  const float inv = 1.f / den;
  float vx = acc.x * inv + bias[2 * lane];
  float vy = acc.y * inv + bias[2 * lane + 1];
  vx = vx > 0.f ? vx : __expf(vx) - 1.f;
  vy = vy > 0.f ? vy : __expf(vy) - 1.f;
  *(float2*)(h1 + (size_t)node * 128 + 2 * lane) = make_float2(vx, vy);
}

// ---------------------------------------------------------------------------
// Layer-2 fused: per dst node (half-wave, 32 ch, 1 head) + log_softmax.
// ---------------------------------------------------------------------------
__global__ __launch_bounds__(256) void gat2_fused(
    const int* __restrict__ row_ofs, const int* __restrict__ src_sorted,
    const float* __restrict__ xs, const float* __restrict__ xd,
    const float* __restrict__ att, const float* __restrict__ bias,
    float* __restrict__ out, int N) {
  const int node = (int)((blockIdx.x * 256u + threadIdx.x) >> 5);
  const int c = threadIdx.x & 31;
  if (node >= N) return;
  const float at = att[c];
  const float xdv = xd[(size_t)node * 32 + c];
  float acc = 0.f, den = 0.f;
  const int b = row_ofs[node], eend = row_ofs[node + 1];
  {
    float m = xs[(size_t)node * 32 + c];
    float p = lrelu(m + xdv) * at;
    p += __shfl_xor(p, 1);
    p += __shfl_xor(p, 2);
    p += __shfl_xor(p, 4);
    p += __shfl_xor(p, 8);
    p += __shfl_xor(p, 16);
    float ex = __expf(p);
    den += ex;
    acc += ex * m;
  }
  int sNext = (b < eend) ? src_sorted[b] : 0;
  for (int e = b; e < eend; e++) {
    const int s = sNext;
    sNext = (e + 1 < eend) ? src_sorted[e + 1] : 0;
    float m = xs[(size_t)s * 32 + c];
    float p = lrelu(m + xdv) * at;
    p += __shfl_xor(p, 1);
    p += __shfl_xor(p, 2);
    p += __shfl_xor(p, 4);
    p += __shfl_xor(p, 8);
    p += __shfl_xor(p, 16);
    float ex = __expf(p);
    den += ex;
    acc += ex * m;
  }
  float v = acc / den + bias[c];
  // log_softmax over the 32 channels
  float mx = v;
  mx = fmaxf(mx, __shfl_xor(mx, 1));
  mx = fmaxf(mx, __shfl_xor(mx, 2));
  mx = fmaxf(mx, __shfl_xor(mx, 4));
  mx = fmaxf(mx, __shfl_xor(mx, 8));
  mx = fmaxf(mx, __shfl_xor(mx, 16));
  float ex = __expf(v - mx);
  float sum = ex;
  sum += __shfl_xor(sum, 1);
  sum += __shfl_xor(sum, 2);
  sum += __shfl_xor(sum, 4);
  sum += __shfl_xor(sum, 8);
  sum += __shfl_xor(sum, 16);
  out[(size_t)node * 32 + c] = v - mx - __logf(sum);
}

extern "C" void kernel_launch(void* const* d_in, const int* in_sizes, int n_in,
                              void* d_out, int out_size, void* d_ws, size_t ws_size,
                              hipStream_t stream) {
  const float* x = (const float*)d_in[0];
  const int* ei = (const int*)d_in[1];
  const float* W1s = (const float*)d_in[2];
  const float* W1d = (const float*)d_in[3];
  const float* b1s = (const float*)d_in[4];
  const float* b1d = (const float*)d_in[5];
  const float* att1 = (const float*)d_in[6];
  const float* bias1 = (const float*)d_in[7];
  const float* W2s = (const float*)d_in[8];
  const float* W2d = (const float*)d_in[9];
  const float* b2s = (const float*)d_in[10];
  const float* b2d = (const float*)d_in[11];
  const float* att2 = (const float*)d_in[12];
  const float* bias2 = (const float*)d_in[13];
  float* out = (float*)d_out;

  const int N = in_sizes[0] / 128;
  const int E = in_sizes[1] / 2;

  float* ws = (float*)d_ws;
  float* xs1 = ws;  ws += (size_t)N * 128;
  float* xd1 = ws;  ws += (size_t)N * 128;
  float* h1 = ws;   ws += (size_t)N * 128;
  float* xs2 = ws;  ws += (size_t)N * 32;
  float* xd2 = ws;  ws += (size_t)N * 32;
  int* count = (int*)ws;       ws += N;
  int* row_ofs = (int*)ws;     ws += N + 1;
  int* wofs = (int*)ws;        ws += N + 1;
  int* src_sorted = (int*)ws;  ws += E;

  hipMemsetAsync(count, 0, (size_t)N * sizeof(int), stream);

  const int eblk = (E + 255) / 256;
  hist_kernel<<<eblk, 256, 0, stream>>>(ei, count, N, E);
  scan_kernel<<<1, 1024, 0, stream>>>(count, row_ofs, wofs, N);
  scatter_kernel<<<eblk, 256, 0, stream>>>(ei, wofs, src_sorted, N, E);

  const int xblocks = (N + 63) / 64;
  xform_kernel<128><<<xblocks, 256, 0, stream>>>(x, W1s, b1s, xs1, N);
  xform_kernel<128><<<xblocks, 256, 0, stream>>>(x, W1d, b1d, xd1, N);

  gat1_fused<<<(N + 3) / 4, 256, 0, stream>>>(row_ofs, src_sorted, xs1, xd1,
                                              att1, bias1, h1, N);

  xform_kernel<32><<<xblocks, 256, 0, stream>>>(h1, W2s, b2s, xs2, N);
  xform_kernel<32><<<xblocks, 256, 0, stream>>>(h1, W2d, b2d, xd2, N);

  gat2_fused<<<(N + 7) / 8, 256, 0, stream>>>(row_ofs, src_sorted, xs2, xd2,
                                              att2, bias2, out, N);
}

// Round 4
// 498.402 us; speedup vs baseline: 1.6272x; 1.6272x over previous
//
#include <hip/hip_runtime.h>
#include <math.h>

#define NEG_SLOPE 0.2f

typedef __attribute__((ext_vector_type(8))) short short8v;
typedef __attribute__((ext_vector_type(4))) float float4v;

__device__ __forceinline__ float lrelu(float x) { return x >= 0.f ? x : NEG_SLOPE * x; }

// round-to-nearest-even fp32 -> bf16 bits
__device__ __forceinline__ unsigned short f2bf(float f) {
  unsigned u = __float_as_uint(f);
  u += 0x7fffu + ((u >> 16) & 1u);
  return (unsigned short)(u >> 16);
}

// ---------------------------------------------------------------------------
// x (fp32) -> bf16, 4 elements per thread
// ---------------------------------------------------------------------------
__global__ __launch_bounds__(256) void cvt_bf16_kernel(
    const float* __restrict__ X, unsigned short* __restrict__ Xb, int total4) {
  int i = blockIdx.x * 256 + threadIdx.x;
  if (i >= total4) return;
  float4 v = ((const float4*)X)[i];
  ushort4 o;
  o.x = f2bf(v.x); o.y = f2bf(v.y); o.z = f2bf(v.z); o.w = f2bf(v.w);
  ((ushort4*)Xb)[i] = o;
}

// ---------------------------------------------------------------------------
// Pack W[128 x C] (fp32, row-major) into MFMA B-fragment layout (bf16):
// frag index (t, kc, lane) holds 8 elems j: W[kc*32 + (lane>>4)*8 + j][t*16 + (lane&15)]
// ---------------------------------------------------------------------------
template <int C>
__global__ __launch_bounds__(256) void pack_w_kernel(
    const float* __restrict__ W, unsigned short* __restrict__ Bp) {
  const int total = (C / 16) * 4 * 64;
  int idx = blockIdx.x * 256 + threadIdx.x;
  if (idx >= total) return;
  int lane = idx & 63;
  int kc = (idx >> 6) & 3;
  int t = idx >> 8;
  int n = t * 16 + (lane & 15);
  int k0 = kc * 32 + (lane >> 4) * 8;
  unsigned short* o = Bp + (size_t)idx * 8;
#pragma unroll
  for (int j = 0; j < 8; j++) o[j] = f2bf(W[(size_t)(k0 + j) * C + n]);
}

// ---------------------------------------------------------------------------
// Y[M x C] = Xb[M x 128](bf16) @ W(bf16, packed frags) + b    via MFMA.
// One wave computes a 16-row x C strip. NT = C/16 column tiles.
// A-frag: lane holds A[m=lane&15][k=(lane>>4)*8+j]; C/D: row=(lane>>4)*4+r, col=lane&15.
// ---------------------------------------------------------------------------
template <int NT>
__global__ __launch_bounds__(256) void mfma_xform(
    const unsigned short* __restrict__ Xb, const unsigned short* __restrict__ Bp,
    const float* __restrict__ b, float* __restrict__ Y, int M) {
  const int wave = threadIdx.x >> 6;
  const int lane = threadIdx.x & 63;
  const int row0 = blockIdx.x * 64 + wave * 16;
  const int m = lane & 15, q = lane >> 4;
  const int arow = min(row0 + m, M - 1);
  const unsigned short* aptr = Xb + (size_t)arow * 128 + q * 8;
  short8v a[4];
#pragma unroll
  for (int kc = 0; kc < 4; kc++) a[kc] = *(const short8v*)(aptr + kc * 32);
  float4v acc[NT];
#pragma unroll
  for (int t = 0; t < NT; t++) acc[t] = (float4v)(0.f);
#pragma unroll
  for (int kc = 0; kc < 4; kc++) {
#pragma unroll
    for (int t = 0; t < NT; t++) {
      short8v bfr = *(const short8v*)(Bp + ((size_t)(t * 4 + kc) * 64 + lane) * 8);
      acc[t] = __builtin_amdgcn_mfma_f32_16x16x32_bf16(a[kc], bfr, acc[t], 0, 0, 0);
    }
  }
#pragma unroll
  for (int t = 0; t < NT; t++) {
    const int col = t * 16 + m;
    const float bc = b[col];
#pragma unroll
    for (int r = 0; r < 4; r++) {
      const int row = row0 + q * 4 + r;
      if (row < M) Y[(size_t)row * (NT * 16) + col] = acc[t][r] + bc;
    }
  }
}

// ---------------------------------------------------------------------------
// CSR build: histogram by dst, exclusive scan, scatter src into dst-order.
// ---------------------------------------------------------------------------
__global__ __launch_bounds__(256) void hist_kernel(
    const int* __restrict__ ei, int* __restrict__ count, int N, int E) {
  int e = blockIdx.x * 256 + threadIdx.x;
  if (e >= E) return;
  int d = ei[E + e];
  d = min(max(d, 0), N - 1);
  atomicAdd(count + d, 1);
}

__global__ __launch_bounds__(1024) void scan_kernel(
    const int* __restrict__ count, int* __restrict__ row_ofs,
    int* __restrict__ wofs, int n) {
  __shared__ int partial[1024];
  const int tid = threadIdx.x;
  const int chunk = (n + 1023) / 1024;
  const int begin = min(tid * chunk, n);
  const int end = min(begin + chunk, n);
  int s = 0;
  for (int i = begin; i < end; i++) s += count[i];
  partial[tid] = s;
  __syncthreads();
  for (int off = 1; off < 1024; off <<= 1) {
    int t = (tid >= off) ? partial[tid - off] : 0;
    __syncthreads();
    partial[tid] += t;
    __syncthreads();
  }
  int running = partial[tid] - s;
  for (int i = begin; i < end; i++) {
    row_ofs[i] = running;
    wofs[i] = running;
    running += count[i];
  }
  if (tid == 1023) row_ofs[n] = partial[1023];
}

__global__ __launch_bounds__(256) void scatter_kernel(
    const int* __restrict__ ei, int* __restrict__ wofs,
    int* __restrict__ src_sorted, int N, int E) {
  int e = blockIdx.x * 256 + threadIdx.x;
  if (e >= E) return;
  int s = ei[e], d = ei[E + e];
  s = min(max(s, 0), N - 1);
  d = min(max(d, 0), N - 1);
  int pos = atomicAdd(wofs + d, 1);
  src_sorted[pos] = s;
}

// ---------------------------------------------------------------------------
// Layer-1 fused: per dst node (one wave): softmax-weighted message mean,
// +bias, ELU; writes h1 as bf16 (input to layer-2 MFMA transforms).
// ---------------------------------------------------------------------------
__global__ __launch_bounds__(256) void gat1_fused(
    const int* __restrict__ row_ofs, const int* __restrict__ src_sorted,
    const float* __restrict__ xs, const float* __restrict__ xd,
    const float* __restrict__ att, const float* __restrict__ bias,
    unsigned short* __restrict__ h1b, int N) {
  const int node = (int)((blockIdx.x * 256u + threadIdx.x) >> 6);
  const int lane = threadIdx.x & 63;
  if (node >= N) return;
  const float2 at = *(const float2*)(att + 2 * lane);
  const float2 xdv = *(const float2*)(xd + (size_t)node * 128 + 2 * lane);
  float2 acc = make_float2(0.f, 0.f);
  float den = 0.f;
  const int b = row_ofs[node], eend = row_ofs[node + 1];
  {
    float2 m = *(const float2*)(xs + (size_t)node * 128 + 2 * lane);
    float p = lrelu(m.x + xdv.x) * at.x + lrelu(m.y + xdv.y) * at.y;
    p += __shfl_xor(p, 1);
    p += __shfl_xor(p, 2);
    p += __shfl_xor(p, 4);
    float ex = __expf(p);
    den += ex;
    acc.x += ex * m.x;
    acc.y += ex * m.y;
  }
  int sNext = (b < eend) ? src_sorted[b] : 0;
  for (int e = b; e < eend; e++) {
    const int s = sNext;
    sNext = (e + 1 < eend) ? src_sorted[e + 1] : 0;
    float2 m = *(const float2*)(xs + (size_t)s * 128 + 2 * lane);
    float p = lrelu(m.x + xdv.x) * at.x + lrelu(m.y + xdv.y) * at.y;
    p += __shfl_xor(p, 1);
    p += __shfl_xor(p, 2);
    p += __shfl_xor(p, 4);
    float ex = __expf(p);
    den += ex;
    acc.x += ex * m.x;
    acc.y += ex * m.y;
  }
  const float inv = 1.f / den;
  float vx = acc.x * inv + bias[2 * lane];
  float vy = acc.y * inv + bias[2 * lane + 1];
  vx = vx > 0.f ? vx : __expf(vx) - 1.f;
  vy = vy > 0.f ? vy : __expf(vy) - 1.f;
  unsigned int packed = (unsigned)f2bf(vx) | ((unsigned)f2bf(vy) << 16);
  ((unsigned int*)h1b)[(size_t)node * 64 + lane] = packed;
}

// ---------------------------------------------------------------------------
// Layer-2 fused: per dst node (half-wave, 32 ch, 1 head) + log_softmax.
// ---------------------------------------------------------------------------
__global__ __launch_bounds__(256) void gat2_fused(
    const int* __restrict__ row_ofs, const int* __restrict__ src_sorted,
    const float* __restrict__ xs, const float* __restrict__ xd,
    const float* __restrict__ att, const float* __restrict__ bias,
    float* __restrict__ out, int N) {
  const int node = (int)((blockIdx.x * 256u + threadIdx.x) >> 5);
  const int c = threadIdx.x & 31;
  if (node >= N) return;
  const float at = att[c];
  const float xdv = xd[(size_t)node * 32 + c];
  float acc = 0.f, den = 0.f;
  const int b = row_ofs[node], eend = row_ofs[node + 1];
  {
    float m = xs[(size_t)node * 32 + c];
    float p = lrelu(m + xdv) * at;
    p += __shfl_xor(p, 1);
    p += __shfl_xor(p, 2);
    p += __shfl_xor(p, 4);
    p += __shfl_xor(p, 8);
    p += __shfl_xor(p, 16);
    float ex = __expf(p);
    den += ex;
    acc += ex * m;
  }
  int sNext = (b < eend) ? src_sorted[b] : 0;
  for (int e = b; e < eend; e++) {
    const int s = sNext;
    sNext = (e + 1 < eend) ? src_sorted[e + 1] : 0;
    float m = xs[(size_t)s * 32 + c];
    float p = lrelu(m + xdv) * at;
    p += __shfl_xor(p, 1);
    p += __shfl_xor(p, 2);
    p += __shfl_xor(p, 4);
    p += __shfl_xor(p, 8);
    p += __shfl_xor(p, 16);
    float ex = __expf(p);
    den += ex;
    acc += ex * m;
  }
  float v = acc / den + bias[c];
  float mx = v;
  mx = fmaxf(mx, __shfl_xor(mx, 1));
  mx = fmaxf(mx, __shfl_xor(mx, 2));
  mx = fmaxf(mx, __shfl_xor(mx, 4));
  mx = fmaxf(mx, __shfl_xor(mx, 8));
  mx = fmaxf(mx, __shfl_xor(mx, 16));
  float ex = __expf(v - mx);
  float sum = ex;
  sum += __shfl_xor(sum, 1);
  sum += __shfl_xor(sum, 2);
  sum += __shfl_xor(sum, 4);
  sum += __shfl_xor(sum, 8);
  sum += __shfl_xor(sum, 16);
  out[(size_t)node * 32 + c] = v - mx - __logf(sum);
}

extern "C" void kernel_launch(void* const* d_in, const int* in_sizes, int n_in,
                              void* d_out, int out_size, void* d_ws, size_t ws_size,
                              hipStream_t stream) {
  const float* x = (const float*)d_in[0];
  const int* ei = (const int*)d_in[1];
  const float* W1s = (const float*)d_in[2];
  const float* W1d = (const float*)d_in[3];
  const float* b1s = (const float*)d_in[4];
  const float* b1d = (const float*)d_in[5];
  const float* att1 = (const float*)d_in[6];
  const float* bias1 = (const float*)d_in[7];
  const float* W2s = (const float*)d_in[8];
  const float* W2d = (const float*)d_in[9];
  const float* b2s = (const float*)d_in[10];
  const float* b2d = (const float*)d_in[11];
  const float* att2 = (const float*)d_in[12];
  const float* bias2 = (const float*)d_in[13];
  float* out = (float*)d_out;

  const int N = in_sizes[0] / 128;
  const int E = in_sizes[1] / 2;

  char* p = (char*)d_ws;
  auto alloc = [&](size_t bytes) { char* r = p; p += (bytes + 63) & ~63ull; return r; };
  float* xs1 = (float*)alloc((size_t)N * 128 * 4);
  float* xd1 = (float*)alloc((size_t)N * 128 * 4);
  float* xs2 = (float*)alloc((size_t)N * 32 * 4);
  float* xd2 = (float*)alloc((size_t)N * 32 * 4);
  unsigned short* xb = (unsigned short*)alloc((size_t)N * 128 * 2);
  unsigned short* h1b = (unsigned short*)alloc((size_t)N * 128 * 2);
  unsigned short* Bp1s = (unsigned short*)alloc(8 * 4 * 64 * 8 * 2);
  unsigned short* Bp1d = (unsigned short*)alloc(8 * 4 * 64 * 8 * 2);
  unsigned short* Bp2s = (unsigned short*)alloc(2 * 4 * 64 * 8 * 2);
  unsigned short* Bp2d = (unsigned short*)alloc(2 * 4 * 64 * 8 * 2);
  int* count = (int*)alloc((size_t)N * 4);
  int* row_ofs = (int*)alloc((size_t)(N + 1) * 4);
  int* wofs = (int*)alloc((size_t)(N + 1) * 4);
  int* src_sorted = (int*)alloc((size_t)E * 4);

  hipMemsetAsync(count, 0, (size_t)N * sizeof(int), stream);

  // prep: bf16 conversions + W fragment packing + CSR build
  const int total4 = N * 128 / 4;
  cvt_bf16_kernel<<<(total4 + 255) / 256, 256, 0, stream>>>(x, xb, total4);
  pack_w_kernel<128><<<8, 256, 0, stream>>>(W1s, Bp1s);
  pack_w_kernel<128><<<8, 256, 0, stream>>>(W1d, Bp1d);
  pack_w_kernel<32><<<2, 256, 0, stream>>>(W2s, Bp2s);
  pack_w_kernel<32><<<2, 256, 0, stream>>>(W2d, Bp2d);

  const int eblk = (E + 255) / 256;
  hist_kernel<<<eblk, 256, 0, stream>>>(ei, count, N, E);
  scan_kernel<<<1, 1024, 0, stream>>>(count, row_ofs, wofs, N);
  scatter_kernel<<<eblk, 256, 0, stream>>>(ei, wofs, src_sorted, N, E);

  const int xblocks = (N + 63) / 64;
  mfma_xform<8><<<xblocks, 256, 0, stream>>>(xb, Bp1s, b1s, xs1, N);
  mfma_xform<8><<<xblocks, 256, 0, stream>>>(xb, Bp1d, b1d, xd1, N);

  gat1_fused<<<(N + 3) / 4, 256, 0, stream>>>(row_ofs, src_sorted, xs1, xd1,
                                              att1, bias1, h1b, N);

  mfma_xform<2><<<xblocks, 256, 0, stream>>>(h1b, Bp2s, b2s, xs2, N);
  mfma_xform<2><<<xblocks, 256, 0, stream>>>(h1b, Bp2d, b2d, xd2, N);

  gat2_fused<<<(N + 7) / 8, 256, 0, stream>>>(row_ofs, src_sorted, xs2, xd2,
                                              att2, bias2, out, N);
}

// Round 5
// 432.363 us; speedup vs baseline: 1.8757x; 1.1527x over previous
//
#include <hip/hip_runtime.h>
#include <math.h>

#define NEG_SLOPE 0.2f

typedef __attribute__((ext_vector_type(8))) short short8v;
typedef __attribute__((ext_vector_type(4))) float float4v;

__device__ __forceinline__ float lrelu(float x) { return fmaxf(x, NEG_SLOPE * x); }

// round-to-nearest-even fp32 -> bf16 bits
__device__ __forceinline__ unsigned short f2bf(float f) {
  unsigned u = __float_as_uint(f);
  u += 0x7fffu + ((u >> 16) & 1u);
  return (unsigned short)(u >> 16);
}
// packed uint(lo,hi bf16) -> two floats
__device__ __forceinline__ float bflo(unsigned v) { return __uint_as_float(v << 16); }
__device__ __forceinline__ float bfhi(unsigned v) { return __uint_as_float(v & 0xffff0000u); }
__device__ __forceinline__ unsigned packbf(float a, float b) {
  return (unsigned)f2bf(a) | ((unsigned)f2bf(b) << 16);
}

// ---------------------------------------------------------------------------
// x (fp32) -> bf16, 4 elements per thread
// ---------------------------------------------------------------------------
__global__ __launch_bounds__(256) void cvt_bf16_kernel(
    const float* __restrict__ X, unsigned short* __restrict__ Xb, int total4) {
  int i = blockIdx.x * 256 + threadIdx.x;
  if (i >= total4) return;
  float4 v = ((const float4*)X)[i];
  ushort4 o;
  o.x = f2bf(v.x); o.y = f2bf(v.y); o.z = f2bf(v.z); o.w = f2bf(v.w);
  ((ushort4*)Xb)[i] = o;
}

// ---------------------------------------------------------------------------
// Pack W[128 x C] (fp32, row-major) into MFMA B-fragment layout (bf16):
// frag (t, kc, lane) holds 8 elems j: W[kc*32 + (lane>>4)*8 + j][t*16 + (lane&15)]
// ---------------------------------------------------------------------------
template <int C>
__global__ __launch_bounds__(256) void pack_w_kernel(
    const float* __restrict__ W, unsigned short* __restrict__ Bp) {
  const int total = (C / 16) * 4 * 64;
  int idx = blockIdx.x * 256 + threadIdx.x;
  if (idx >= total) return;
  int lane = idx & 63;
  int kc = (idx >> 6) & 3;
  int t = idx >> 8;
  int n = t * 16 + (lane & 15);
  int k0 = kc * 32 + (lane >> 4) * 8;
  unsigned short* o = Bp + (size_t)idx * 8;
#pragma unroll
  for (int j = 0; j < 8; j++) o[j] = f2bf(W[(size_t)(k0 + j) * C + n]);
}

// ---------------------------------------------------------------------------
// Merged transform: Ys = Xb@Ws + bs, Yd = Xb@Wd + bd, outputs packed bf16
// (uint per 2 adjacent channels). One wave: 16 rows x C. NT = C/16.
// A-frag: lane holds A[m=lane&15][k=(lane>>4)*8+j]; C/D: row=(lane>>4)*4+r, col=lane&15.
// Column-pair packing via __shfl_xor(v,1); even-m lanes store.
// ---------------------------------------------------------------------------
template <int NT>
__global__ __launch_bounds__(256) void mfma_xform2(
    const unsigned short* __restrict__ Xb,
    const unsigned short* __restrict__ BpS, const unsigned short* __restrict__ BpD,
    const float* __restrict__ bS, const float* __restrict__ bD,
    unsigned int* __restrict__ Ys, unsigned int* __restrict__ Yd, int M) {
  const int wave = threadIdx.x >> 6;
  const int lane = threadIdx.x & 63;
  const int row0 = blockIdx.x * 64 + wave * 16;
  const int m = lane & 15, q = lane >> 4;
  const int arow = min(row0 + m, M - 1);
  const unsigned short* aptr = Xb + (size_t)arow * 128 + q * 8;
  short8v a[4];
#pragma unroll
  for (int kc = 0; kc < 4; kc++) a[kc] = *(const short8v*)(aptr + kc * 32);
  float4v accS[NT], accD[NT];
#pragma unroll
  for (int t = 0; t < NT; t++) { accS[t] = (float4v)(0.f); accD[t] = (float4v)(0.f); }
#pragma unroll
  for (int kc = 0; kc < 4; kc++) {
#pragma unroll
    for (int t = 0; t < NT; t++) {
      short8v bs = *(const short8v*)(BpS + ((size_t)(t * 4 + kc) * 64 + lane) * 8);
      short8v bd = *(const short8v*)(BpD + ((size_t)(t * 4 + kc) * 64 + lane) * 8);
      accS[t] = __builtin_amdgcn_mfma_f32_16x16x32_bf16(a[kc], bs, accS[t], 0, 0, 0);
      accD[t] = __builtin_amdgcn_mfma_f32_16x16x32_bf16(a[kc], bd, accD[t], 0, 0, 0);
    }
  }
  const bool even = (m & 1) == 0;
#pragma unroll
  for (int t = 0; t < NT; t++) {
    const int col = t * 16 + m;
    const float bcS = bS[col], bcD = bD[col];
#pragma unroll
    for (int r = 0; r < 4; r++) {
      const int row = row0 + q * 4 + r;
      float vS = accS[t][r] + bcS;
      float vD = accD[t][r] + bcD;
      float pS = __shfl_xor(vS, 1);
      float pD = __shfl_xor(vD, 1);
      if (even && row < M) {
        size_t idx = (size_t)row * (NT * 8) + t * 8 + (m >> 1);
        Ys[idx] = packbf(vS, pS);
        Yd[idx] = packbf(vD, pD);
      }
    }
  }
}

// ---------------------------------------------------------------------------
// CSR build: histogram by dst, exclusive scan, scatter src into dst-order.
// ---------------------------------------------------------------------------
__global__ __launch_bounds__(256) void hist_kernel(
    const int* __restrict__ ei, int* __restrict__ count, int N, int E) {
  int e = blockIdx.x * 256 + threadIdx.x;
  if (e >= E) return;
  int d = ei[E + e];
  d = min(max(d, 0), N - 1);
  atomicAdd(count + d, 1);
}

__global__ __launch_bounds__(1024) void scan_kernel(
    const int* __restrict__ count, int* __restrict__ row_ofs,
    int* __restrict__ wofs, int n) {
  __shared__ int partial[1024];
  const int tid = threadIdx.x;
  const int chunk = (n + 1023) / 1024;
  const int begin = min(tid * chunk, n);
  const int end = min(begin + chunk, n);
  int s = 0;
  for (int i = begin; i < end; i++) s += count[i];
  partial[tid] = s;
  __syncthreads();
  for (int off = 1; off < 1024; off <<= 1) {
    int t = (tid >= off) ? partial[tid - off] : 0;
    __syncthreads();
    partial[tid] += t;
    __syncthreads();
  }
  int running = partial[tid] - s;
  for (int i = begin; i < end; i++) {
    row_ofs[i] = running;
    wofs[i] = running;
    running += count[i];
  }
  if (tid == 1023) row_ofs[n] = partial[1023];
}

__global__ __launch_bounds__(256) void scatter_kernel(
    const int* __restrict__ ei, int* __restrict__ wofs,
    int* __restrict__ src_sorted, int N, int E) {
  int e = blockIdx.x * 256 + threadIdx.x;
  if (e >= E) return;
  int s = ei[e], d = ei[E + e];
  s = min(max(s, 0), N - 1);
  d = min(max(d, 0), N - 1);
  int pos = atomicAdd(wofs + d, 1);
  src_sorted[pos] = s;
}

// ---------------------------------------------------------------------------
// Layer-1 fused: one wave per dst node; bf16-packed rows (64 uints = 128 ch).
// lane covers channels 2l,2l+1; head h = lane/8; softmax-weighted mean,
// +bias, ELU; writes h1 packed bf16.
// ---------------------------------------------------------------------------
__global__ __launch_bounds__(256) void gat1_fused(
    const int* __restrict__ row_ofs, const int* __restrict__ src_sorted,
    const unsigned int* __restrict__ xsb, const unsigned int* __restrict__ xdb,
    const float* __restrict__ att, const float* __restrict__ bias,
    unsigned int* __restrict__ h1b, int N) {
  const int node = (int)((blockIdx.x * 256u + threadIdx.x) >> 6);
  const int lane = threadIdx.x & 63;
  if (node >= N) return;
  const float2 at = *(const float2*)(att + 2 * lane);
  const unsigned xdp = xdb[(size_t)node * 64 + lane];
  const float xdx = bflo(xdp), xdy = bfhi(xdp);
  float accx = 0.f, accy = 0.f, den = 0.f;
  const int b = row_ofs[node], eend = row_ofs[node + 1];
  // self-loop
  {
    unsigned mp = xsb[(size_t)node * 64 + lane];
    float mx = bflo(mp), my = bfhi(mp);
    float p = lrelu(mx + xdx) * at.x + lrelu(my + xdy) * at.y;
    p += __shfl_xor(p, 1);
    p += __shfl_xor(p, 2);
    p += __shfl_xor(p, 4);
    float ex = __expf(p);
    den += ex; accx += ex * mx; accy += ex * my;
  }
  unsigned mNext = 0;
  if (b < eend) {
    int s0 = src_sorted[b];
    mNext = xsb[(size_t)s0 * 64 + lane];
  }
  for (int e = b; e < eend; e++) {
    const unsigned mp = mNext;
    if (e + 1 < eend) {
      int sn = src_sorted[e + 1];
      mNext = xsb[(size_t)sn * 64 + lane];
    }
    float mx = bflo(mp), my = bfhi(mp);
    float p = lrelu(mx + xdx) * at.x + lrelu(my + xdy) * at.y;
    p += __shfl_xor(p, 1);
    p += __shfl_xor(p, 2);
    p += __shfl_xor(p, 4);
    float ex = __expf(p);
    den += ex; accx += ex * mx; accy += ex * my;
  }
  const float inv = 1.f / den;
  const float2 bc = *(const float2*)(bias + 2 * lane);
  float vx = accx * inv + bc.x;
  float vy = accy * inv + bc.y;
  vx = vx > 0.f ? vx : __expf(vx) - 1.f;
  vy = vy > 0.f ? vy : __expf(vy) - 1.f;
  h1b[(size_t)node * 64 + lane] = packbf(vx, vy);
}

// ---------------------------------------------------------------------------
// Layer-2 fused: 16 lanes per dst node (4 nodes/wave), 2 ch/lane bf16,
// 1 head + log_softmax; writes fp32 output.
// ---------------------------------------------------------------------------
__global__ __launch_bounds__(256) void gat2_fused(
    const int* __restrict__ row_ofs, const int* __restrict__ src_sorted,
    const unsigned int* __restrict__ xsb, const unsigned int* __restrict__ xdb,
    const float* __restrict__ att, const float* __restrict__ bias,
    float* __restrict__ out, int N) {
  const int node = (int)((blockIdx.x * 256u + threadIdx.x) >> 4);
  const int q = threadIdx.x & 15;
  if (node >= N) return;
  const float2 at = *(const float2*)(att + 2 * q);
  const unsigned xdp = xdb[(size_t)node * 16 + q];
  const float xdx = bflo(xdp), xdy = bfhi(xdp);
  float accx = 0.f, accy = 0.f, den = 0.f;
  const int b = row_ofs[node], eend = row_ofs[node + 1];
  {
    unsigned mp = xsb[(size_t)node * 16 + q];
    float mx = bflo(mp), my = bfhi(mp);
    float p = lrelu(mx + xdx) * at.x + lrelu(my + xdy) * at.y;
    p += __shfl_xor(p, 1);
    p += __shfl_xor(p, 2);
    p += __shfl_xor(p, 4);
    p += __shfl_xor(p, 8);
    float ex = __expf(p);
    den += ex; accx += ex * mx; accy += ex * my;
  }
  unsigned mNext = 0;
  if (b < eend) {
    int s0 = src_sorted[b];
    mNext = xsb[(size_t)s0 * 16 + q];
  }
  for (int e = b; e < eend; e++) {
    const unsigned mp = mNext;
    if (e + 1 < eend) {
      int sn = src_sorted[e + 1];
      mNext = xsb[(size_t)sn * 16 + q];
    }
    float mx = bflo(mp), my = bfhi(mp);
    float p = lrelu(mx + xdx) * at.x + lrelu(my + xdy) * at.y;
    p += __shfl_xor(p, 1);
    p += __shfl_xor(p, 2);
    p += __shfl_xor(p, 4);
    p += __shfl_xor(p, 8);
    float ex = __expf(p);
    den += ex; accx += ex * mx; accy += ex * my;
  }
  const float inv = 1.f / den;
  const float2 bc = *(const float2*)(bias + 2 * q);
  float v0 = accx * inv + bc.x;
  float v1 = accy * inv + bc.y;
  // log_softmax over 32 channels (2 local x 16 lanes)
  float mx2 = fmaxf(v0, v1);
  mx2 = fmaxf(mx2, __shfl_xor(mx2, 1));
  mx2 = fmaxf(mx2, __shfl_xor(mx2, 2));
  mx2 = fmaxf(mx2, __shfl_xor(mx2, 4));
  mx2 = fmaxf(mx2, __shfl_xor(mx2, 8));
  float sum = __expf(v0 - mx2) + __expf(v1 - mx2);
  sum += __shfl_xor(sum, 1);
  sum += __shfl_xor(sum, 2);
  sum += __shfl_xor(sum, 4);
  sum += __shfl_xor(sum, 8);
  const float lse = mx2 + __logf(sum);
  *(float2*)(out + (size_t)node * 32 + 2 * q) = make_float2(v0 - lse, v1 - lse);
}

extern "C" void kernel_launch(void* const* d_in, const int* in_sizes, int n_in,
                              void* d_out, int out_size, void* d_ws, size_t ws_size,
                              hipStream_t stream) {
  const float* x = (const float*)d_in[0];
  const int* ei = (const int*)d_in[1];
  const float* W1s = (const float*)d_in[2];
  const float* W1d = (const float*)d_in[3];
  const float* b1s = (const float*)d_in[4];
  const float* b1d = (const float*)d_in[5];
  const float* att1 = (const float*)d_in[6];
  const float* bias1 = (const float*)d_in[7];
  const float* W2s = (const float*)d_in[8];
  const float* W2d = (const float*)d_in[9];
  const float* b2s = (const float*)d_in[10];
  const float* b2d = (const float*)d_in[11];
  const float* att2 = (const float*)d_in[12];
  const float* bias2 = (const float*)d_in[13];
  float* out = (float*)d_out;

  const int N = in_sizes[0] / 128;
  const int E = in_sizes[1] / 2;

  char* p = (char*)d_ws;
  auto alloc = [&](size_t bytes) { char* r = p; p += (bytes + 63) & ~63ull; return r; };
  unsigned int* xs1b = (unsigned int*)alloc((size_t)N * 64 * 4);
  unsigned int* xd1b = (unsigned int*)alloc((size_t)N * 64 * 4);
  unsigned int* xs2b = (unsigned int*)alloc((size_t)N * 16 * 4);
  unsigned int* xd2b = (unsigned int*)alloc((size_t)N * 16 * 4);
  unsigned short* xb = (unsigned short*)alloc((size_t)N * 128 * 2);
  unsigned int* h1b = (unsigned int*)alloc((size_t)N * 64 * 4);
  unsigned short* Bp1s = (unsigned short*)alloc(8 * 4 * 64 * 8 * 2);
  unsigned short* Bp1d = (unsigned short*)alloc(8 * 4 * 64 * 8 * 2);
  unsigned short* Bp2s = (unsigned short*)alloc(2 * 4 * 64 * 8 * 2);
  unsigned short* Bp2d = (unsigned short*)alloc(2 * 4 * 64 * 8 * 2);
  int* count = (int*)alloc((size_t)N * 4);
  int* row_ofs = (int*)alloc((size_t)(N + 1) * 4);
  int* wofs = (int*)alloc((size_t)(N + 1) * 4);
  int* src_sorted = (int*)alloc((size_t)E * 4);

  hipMemsetAsync(count, 0, (size_t)N * sizeof(int), stream);

  const int total4 = N * 128 / 4;
  cvt_bf16_kernel<<<(total4 + 255) / 256, 256, 0, stream>>>(x, xb, total4);
  pack_w_kernel<128><<<8, 256, 0, stream>>>(W1s, Bp1s);
  pack_w_kernel<128><<<8, 256, 0, stream>>>(W1d, Bp1d);
  pack_w_kernel<32><<<2, 256, 0, stream>>>(W2s, Bp2s);
  pack_w_kernel<32><<<2, 256, 0, stream>>>(W2d, Bp2d);

  const int eblk = (E + 255) / 256;
  hist_kernel<<<eblk, 256, 0, stream>>>(ei, count, N, E);
  scan_kernel<<<1, 1024, 0, stream>>>(count, row_ofs, wofs, N);
  scatter_kernel<<<eblk, 256, 0, stream>>>(ei, wofs, src_sorted, N, E);

  const int xblocks = (N + 63) / 64;
  mfma_xform2<8><<<xblocks, 256, 0, stream>>>(xb, Bp1s, Bp1d, b1s, b1d, xs1b, xd1b, N);

  gat1_fused<<<(N + 3) / 4, 256, 0, stream>>>(row_ofs, src_sorted, xs1b, xd1b,
                                              att1, bias1, h1b, N);

  mfma_xform2<2><<<xblocks, 256, 0, stream>>>((const unsigned short*)h1b, Bp2s, Bp2d,
                                              b2s, b2d, xs2b, xd2b, N);

  gat2_fused<<<(N + 15) / 16, 256, 0, stream>>>(row_ofs, src_sorted, xs2b, xd2b,
                                                att2, bias2, out, N);
}

// Round 6
// 341.961 us; speedup vs baseline: 2.3716x; 1.2644x over previous
//
#include <hip/hip_runtime.h>
#include <math.h>

#define NEG_SLOPE 0.2f

typedef __attribute__((ext_vector_type(8))) short short8v;
typedef __attribute__((ext_vector_type(4))) float float4v;

__device__ __forceinline__ float lrelu(float x) { return fmaxf(x, NEG_SLOPE * x); }

// round-to-nearest-even fp32 -> bf16 bits
__device__ __forceinline__ unsigned short f2bf(float f) {
  unsigned u = __float_as_uint(f);
  u += 0x7fffu + ((u >> 16) & 1u);
  return (unsigned short)(u >> 16);
}
// packed uint(lo,hi bf16) -> two floats
__device__ __forceinline__ float bflo(unsigned v) { return __uint_as_float(v << 16); }
__device__ __forceinline__ float bfhi(unsigned v) { return __uint_as_float(v & 0xffff0000u); }
__device__ __forceinline__ unsigned packbf(float a, float b) {
  return (unsigned)f2bf(a) | ((unsigned)f2bf(b) << 16);
}

// ---------------------------------------------------------------------------
// x (fp32) -> bf16, 4 elements per thread
// ---------------------------------------------------------------------------
__global__ __launch_bounds__(256) void cvt_bf16_kernel(
    const float* __restrict__ X, unsigned short* __restrict__ Xb, int total4) {
  int i = blockIdx.x * 256 + threadIdx.x;
  if (i >= total4) return;
  float4 v = ((const float4*)X)[i];
  ushort4 o;
  o.x = f2bf(v.x); o.y = f2bf(v.y); o.z = f2bf(v.z); o.w = f2bf(v.w);
  ((ushort4*)Xb)[i] = o;
}

// ---------------------------------------------------------------------------
// Pack W[128 x C] (fp32, row-major) into MFMA B-fragment layout (bf16):
// frag (t, kc, lane) holds 8 elems j: W[kc*32 + (lane>>4)*8 + j][t*16 + (lane&15)]
// ---------------------------------------------------------------------------
template <int C>
__global__ __launch_bounds__(256) void pack_w_kernel(
    const float* __restrict__ W, unsigned short* __restrict__ Bp) {
  const int total = (C / 16) * 4 * 64;
  int idx = blockIdx.x * 256 + threadIdx.x;
  if (idx >= total) return;
  int lane = idx & 63;
  int kc = (idx >> 6) & 3;
  int t = idx >> 8;
  int n = t * 16 + (lane & 15);
  int k0 = kc * 32 + (lane >> 4) * 8;
  unsigned short* o = Bp + (size_t)idx * 8;
#pragma unroll
  for (int j = 0; j < 8; j++) o[j] = f2bf(W[(size_t)(k0 + j) * C + n]);
}

// ---------------------------------------------------------------------------
// Merged transform: Ys = Xb@Ws + bs, Yd = Xb@Wd + bd, outputs packed bf16.
// ---------------------------------------------------------------------------
template <int NT>
__global__ __launch_bounds__(256) void mfma_xform2(
    const unsigned short* __restrict__ Xb,
    const unsigned short* __restrict__ BpS, const unsigned short* __restrict__ BpD,
    const float* __restrict__ bS, const float* __restrict__ bD,
    unsigned int* __restrict__ Ys, unsigned int* __restrict__ Yd, int M) {
  const int wave = threadIdx.x >> 6;
  const int lane = threadIdx.x & 63;
  const int row0 = blockIdx.x * 64 + wave * 16;
  const int m = lane & 15, q = lane >> 4;
  const int arow = min(row0 + m, M - 1);
  const unsigned short* aptr = Xb + (size_t)arow * 128 + q * 8;
  short8v a[4];
#pragma unroll
  for (int kc = 0; kc < 4; kc++) a[kc] = *(const short8v*)(aptr + kc * 32);
  float4v accS[NT], accD[NT];
#pragma unroll
  for (int t = 0; t < NT; t++) { accS[t] = (float4v)(0.f); accD[t] = (float4v)(0.f); }
#pragma unroll
  for (int kc = 0; kc < 4; kc++) {
#pragma unroll
    for (int t = 0; t < NT; t++) {
      short8v bs = *(const short8v*)(BpS + ((size_t)(t * 4 + kc) * 64 + lane) * 8);
      short8v bd = *(const short8v*)(BpD + ((size_t)(t * 4 + kc) * 64 + lane) * 8);
      accS[t] = __builtin_amdgcn_mfma_f32_16x16x32_bf16(a[kc], bs, accS[t], 0, 0, 0);
      accD[t] = __builtin_amdgcn_mfma_f32_16x16x32_bf16(a[kc], bd, accD[t], 0, 0, 0);
    }
  }
  const bool even = (m & 1) == 0;
#pragma unroll
  for (int t = 0; t < NT; t++) {
    const int col = t * 16 + m;
    const float bcS = bS[col], bcD = bD[col];
#pragma unroll
    for (int r = 0; r < 4; r++) {
      const int row = row0 + q * 4 + r;
      float vS = accS[t][r] + bcS;
      float vD = accD[t][r] + bcD;
      float pS = __shfl_xor(vS, 1);
      float pD = __shfl_xor(vD, 1);
      if (even && row < M) {
        size_t idx = (size_t)row * (NT * 8) + t * 8 + (m >> 1);
        Ys[idx] = packbf(vS, pS);
        Yd[idx] = packbf(vD, pD);
      }
    }
  }
}

// ---------------------------------------------------------------------------
// CSR build: histogram by dst, 3-kernel hierarchical exclusive scan, scatter.
// ---------------------------------------------------------------------------
__global__ __launch_bounds__(256) void hist_kernel(
    const int* __restrict__ ei, int* __restrict__ count, int N, int E) {
  int e = blockIdx.x * 256 + threadIdx.x;
  if (e >= E) return;
  int d = ei[E + e];
  d = min(max(d, 0), N - 1);
  atomicAdd(count + d, 1);
}

// block b sums count[b*2048 .. b*2048+2047] -> bsum[b]
__global__ __launch_bounds__(256) void scan_partial(
    const int* __restrict__ count, int* __restrict__ bsum, int n) {
  const int tid = threadIdx.x;
  const int base = blockIdx.x * 2048 + tid * 8;
  int s = 0;
#pragma unroll
  for (int j = 0; j < 8; j++) {
    int idx = base + j;
    if (idx < n) s += count[idx];
  }
#pragma unroll
  for (int off = 1; off < 64; off <<= 1) s += __shfl_xor(s, off);
  __shared__ int ws[4];
  if ((tid & 63) == 0) ws[tid >> 6] = s;
  __syncthreads();
  if (tid == 0) bsum[blockIdx.x] = ws[0] + ws[1] + ws[2] + ws[3];
}

// single wave: exclusive scan of nblk block sums (carry loop, generic nblk)
__global__ __launch_bounds__(64) void scan_bsums(
    const int* __restrict__ bsum, int* __restrict__ bofs,
    int* __restrict__ row_ofs, int nblk, int n) {
  const int lane = threadIdx.x;
  int carry = 0;
  for (int b0 = 0; b0 < nblk; b0 += 64) {
    int i = b0 + lane;
    int v = (i < nblk) ? bsum[i] : 0;
    int incl = v;
#pragma unroll
    for (int off = 1; off < 64; off <<= 1) {
      int t = __shfl_up(incl, off);
      if (lane >= off) incl += t;
    }
    if (i < nblk) bofs[i] = carry + incl - v;
    carry += __shfl(incl, 63);
  }
  if (lane == 0) row_ofs[n] = carry;
}

// block b: exclusive scan within its 2048 counts + block base
__global__ __launch_bounds__(256) void scan_final(
    const int* __restrict__ count, const int* __restrict__ bofs,
    int* __restrict__ row_ofs, int* __restrict__ wofs, int n) {
  const int tid = threadIdx.x;
  const int lane = tid & 63;
  const int wid = tid >> 6;
  const int base = blockIdx.x * 2048 + tid * 8;
  int c[8];
  int s = 0;
#pragma unroll
  for (int j = 0; j < 8; j++) {
    int idx = base + j;
    c[j] = (idx < n) ? count[idx] : 0;
    s += c[j];
  }
  int incl = s;
#pragma unroll
  for (int off = 1; off < 64; off <<= 1) {
    int t = __shfl_up(incl, off);
    if (lane >= off) incl += t;
  }
  __shared__ int ws[4];
  if (lane == 63) ws[wid] = incl;
  __syncthreads();
  int wbase = 0;
  for (int w = 0; w < wid; w++) wbase += ws[w];
  int running = bofs[blockIdx.x] + wbase + incl - s;
#pragma unroll
  for (int j = 0; j < 8; j++) {
    int idx = base + j;
    if (idx < n) {
      row_ofs[idx] = running;
      wofs[idx] = running;
      running += c[j];
    }
  }
}

__global__ __launch_bounds__(256) void scatter_kernel(
    const int* __restrict__ ei, int* __restrict__ wofs,
    int* __restrict__ src_sorted, int N, int E) {
  int e = blockIdx.x * 256 + threadIdx.x;
  if (e >= E) return;
  int s = ei[e], d = ei[E + e];
  s = min(max(s, 0), N - 1);
  d = min(max(d, 0), N - 1);
  int pos = atomicAdd(wofs + d, 1);
  src_sorted[pos] = s;
}

// ---------------------------------------------------------------------------
// Layer-1 fused: one wave per dst node; bf16-packed rows (64 uints = 128 ch).
// ---------------------------------------------------------------------------
__global__ __launch_bounds__(256) void gat1_fused(
    const int* __restrict__ row_ofs, const int* __restrict__ src_sorted,
    const unsigned int* __restrict__ xsb, const unsigned int* __restrict__ xdb,
    const float* __restrict__ att, const float* __restrict__ bias,
    unsigned int* __restrict__ h1b, int N) {
  const int node = (int)((blockIdx.x * 256u + threadIdx.x) >> 6);
  const int lane = threadIdx.x & 63;
  if (node >= N) return;
  const float2 at = *(const float2*)(att + 2 * lane);
  const unsigned xdp = xdb[(size_t)node * 64 + lane];
  const float xdx = bflo(xdp), xdy = bfhi(xdp);
  float accx = 0.f, accy = 0.f, den = 0.f;
  const int b = row_ofs[node], eend = row_ofs[node + 1];
  // self-loop
  {
    unsigned mp = xsb[(size_t)node * 64 + lane];
    float mx = bflo(mp), my = bfhi(mp);
    float p = lrelu(mx + xdx) * at.x + lrelu(my + xdy) * at.y;
    p += __shfl_xor(p, 1);
    p += __shfl_xor(p, 2);
    p += __shfl_xor(p, 4);
    float ex = __expf(p);
    den += ex; accx += ex * mx; accy += ex * my;
  }
  unsigned mNext = 0;
  if (b < eend) {
    int s0 = src_sorted[b];
    mNext = xsb[(size_t)s0 * 64 + lane];
  }
  for (int e = b; e < eend; e++) {
    const unsigned mp = mNext;
    if (e + 1 < eend) {
      int sn = src_sorted[e + 1];
      mNext = xsb[(size_t)sn * 64 + lane];
    }
    float mx = bflo(mp), my = bfhi(mp);
    float p = lrelu(mx + xdx) * at.x + lrelu(my + xdy) * at.y;
    p += __shfl_xor(p, 1);
    p += __shfl_xor(p, 2);
    p += __shfl_xor(p, 4);
    float ex = __expf(p);
    den += ex; accx += ex * mx; accy += ex * my;
  }
  const float inv = 1.f / den;
  const float2 bc = *(const float2*)(bias + 2 * lane);
  float vx = accx * inv + bc.x;
  float vy = accy * inv + bc.y;
  vx = vx > 0.f ? vx : __expf(vx) - 1.f;
  vy = vy > 0.f ? vy : __expf(vy) - 1.f;
  h1b[(size_t)node * 64 + lane] = packbf(vx, vy);
}

// ---------------------------------------------------------------------------
// Layer-2 fused: 16 lanes per dst node (4 nodes/wave), 2 ch/lane bf16,
// 1 head + log_softmax; writes fp32 output.
// ---------------------------------------------------------------------------
__global__ __launch_bounds__(256) void gat2_fused(
    const int* __restrict__ row_ofs, const int* __restrict__ src_sorted,
    const unsigned int* __restrict__ xsb, const unsigned int* __restrict__ xdb,
    const float* __restrict__ att, const float* __restrict__ bias,
    float* __restrict__ out, int N) {
  const int node = (int)((blockIdx.x * 256u + threadIdx.x) >> 4);
  const int q = threadIdx.x & 15;
  if (node >= N) return;
  const float2 at = *(const float2*)(att + 2 * q);
  const unsigned xdp = xdb[(size_t)node * 16 + q];
  const float xdx = bflo(xdp), xdy = bfhi(xdp);
  float accx = 0.f, accy = 0.f, den = 0.f;
  const int b = row_ofs[node], eend = row_ofs[node + 1];
  {
    unsigned mp = xsb[(size_t)node * 16 + q];
    float mx = bflo(mp), my = bfhi(mp);
    float p = lrelu(mx + xdx) * at.x + lrelu(my + xdy) * at.y;
    p += __shfl_xor(p, 1);
    p += __shfl_xor(p, 2);
    p += __shfl_xor(p, 4);
    p += __shfl_xor(p, 8);
    float ex = __expf(p);
    den += ex; accx += ex * mx; accy += ex * my;
  }
  unsigned mNext = 0;
  if (b < eend) {
    int s0 = src_sorted[b];
    mNext = xsb[(size_t)s0 * 16 + q];
  }
  for (int e = b; e < eend; e++) {
    const unsigned mp = mNext;
    if (e + 1 < eend) {
      int sn = src_sorted[e + 1];
      mNext = xsb[(size_t)sn * 16 + q];
    }
    float mx = bflo(mp), my = bfhi(mp);
    float p = lrelu(mx + xdx) * at.x + lrelu(my + xdy) * at.y;
    p += __shfl_xor(p, 1);
    p += __shfl_xor(p, 2);
    p += __shfl_xor(p, 4);
    p += __shfl_xor(p, 8);
    float ex = __expf(p);
    den += ex; accx += ex * mx; accy += ex * my;
  }
  const float inv = 1.f / den;
  const float2 bc = *(const float2*)(bias + 2 * q);
  float v0 = accx * inv + bc.x;
  float v1 = accy * inv + bc.y;
  float mx2 = fmaxf(v0, v1);
  mx2 = fmaxf(mx2, __shfl_xor(mx2, 1));
  mx2 = fmaxf(mx2, __shfl_xor(mx2, 2));
  mx2 = fmaxf(mx2, __shfl_xor(mx2, 4));
  mx2 = fmaxf(mx2, __shfl_xor(mx2, 8));
  float sum = __expf(v0 - mx2) + __expf(v1 - mx2);
  sum += __shfl_xor(sum, 1);
  sum += __shfl_xor(sum, 2);
  sum += __shfl_xor(sum, 4);
  sum += __shfl_xor(sum, 8);
  const float lse = mx2 + __logf(sum);
  *(float2*)(out + (size_t)node * 32 + 2 * q) = make_float2(v0 - lse, v1 - lse);
}

extern "C" void kernel_launch(void* const* d_in, const int* in_sizes, int n_in,
                              void* d_out, int out_size, void* d_ws, size_t ws_size,
                              hipStream_t stream) {
  const float* x = (const float*)d_in[0];
  const int* ei = (const int*)d_in[1];
  const float* W1s = (const float*)d_in[2];
  const float* W1d = (const float*)d_in[3];
  const float* b1s = (const float*)d_in[4];
  const float* b1d = (const float*)d_in[5];
  const float* att1 = (const float*)d_in[6];
  const float* bias1 = (const float*)d_in[7];
  const float* W2s = (const float*)d_in[8];
  const float* W2d = (const float*)d_in[9];
  const float* b2s = (const float*)d_in[10];
  const float* b2d = (const float*)d_in[11];
  const float* att2 = (const float*)d_in[12];
  const float* bias2 = (const float*)d_in[13];
  float* out = (float*)d_out;

  const int N = in_sizes[0] / 128;
  const int E = in_sizes[1] / 2;

  char* p = (char*)d_ws;
  auto alloc = [&](size_t bytes) { char* r = p; p += (bytes + 63) & ~63ull; return r; };
  unsigned int* xs1b = (unsigned int*)alloc((size_t)N * 64 * 4);
  unsigned int* xd1b = (unsigned int*)alloc((size_t)N * 64 * 4);
  unsigned int* xs2b = (unsigned int*)alloc((size_t)N * 16 * 4);
  unsigned int* xd2b = (unsigned int*)alloc((size_t)N * 16 * 4);
  unsigned short* xb = (unsigned short*)alloc((size_t)N * 128 * 2);
  unsigned int* h1b = (unsigned int*)alloc((size_t)N * 64 * 4);
  unsigned short* Bp1s = (unsigned short*)alloc(8 * 4 * 64 * 8 * 2);
  unsigned short* Bp1d = (unsigned short*)alloc(8 * 4 * 64 * 8 * 2);
  unsigned short* Bp2s = (unsigned short*)alloc(2 * 4 * 64 * 8 * 2);
  unsigned short* Bp2d = (unsigned short*)alloc(2 * 4 * 64 * 8 * 2);
  int* count = (int*)alloc((size_t)N * 4);
  int* row_ofs = (int*)alloc((size_t)(N + 1) * 4);
  int* wofs = (int*)alloc((size_t)(N + 1) * 4);
  int* src_sorted = (int*)alloc((size_t)E * 4);
  const int nsblk = (N + 2047) / 2048;
  int* bsum = (int*)alloc((size_t)nsblk * 4);
  int* bofs = (int*)alloc((size_t)nsblk * 4);

  hipMemsetAsync(count, 0, (size_t)N * sizeof(int), stream);

  const int total4 = N * 128 / 4;
  cvt_bf16_kernel<<<(total4 + 255) / 256, 256, 0, stream>>>(x, xb, total4);
  pack_w_kernel<128><<<8, 256, 0, stream>>>(W1s, Bp1s);
  pack_w_kernel<128><<<8, 256, 0, stream>>>(W1d, Bp1d);
  pack_w_kernel<32><<<2, 256, 0, stream>>>(W2s, Bp2s);
  pack_w_kernel<32><<<2, 256, 0, stream>>>(W2d, Bp2d);

  const int eblk = (E + 255) / 256;
  hist_kernel<<<eblk, 256, 0, stream>>>(ei, count, N, E);
  scan_partial<<<nsblk, 256, 0, stream>>>(count, bsum, N);
  scan_bsums<<<1, 64, 0, stream>>>(bsum, bofs, row_ofs, nsblk, N);
  scan_final<<<nsblk, 256, 0, stream>>>(count, bofs, row_ofs, wofs, N);
  scatter_kernel<<<eblk, 256, 0, stream>>>(ei, wofs, src_sorted, N, E);

  const int xblocks = (N + 63) / 64;
  mfma_xform2<8><<<xblocks, 256, 0, stream>>>(xb, Bp1s, Bp1d, b1s, b1d, xs1b, xd1b, N);

  gat1_fused<<<(N + 3) / 4, 256, 0, stream>>>(row_ofs, src_sorted, xs1b, xd1b,
                                              att1, bias1, h1b, N);

  mfma_xform2<2><<<xblocks, 256, 0, stream>>>((const unsigned short*)h1b, Bp2s, Bp2d,
                                              b2s, b2d, xs2b, xd2b, N);

  gat2_fused<<<(N + 15) / 16, 256, 0, stream>>>(row_ofs, src_sorted, xs2b, xd2b,
                                                att2, bias2, out, N);
}

// Round 7
// 314.684 us; speedup vs baseline: 2.5772x; 1.0867x over previous
//
#include <hip/hip_runtime.h>
#include <math.h>

#define NEG_SLOPE 0.2f

typedef __attribute__((ext_vector_type(8))) short short8v;
typedef __attribute__((ext_vector_type(4))) float float4v;

__device__ __forceinline__ float lrelu(float x) { return fmaxf(x, NEG_SLOPE * x); }

// round-to-nearest-even fp32 -> bf16 bits
__device__ __forceinline__ unsigned short f2bf(float f) {
  unsigned u = __float_as_uint(f);
  u += 0x7fffu + ((u >> 16) & 1u);
  return (unsigned short)(u >> 16);
}
__device__ __forceinline__ float bflo(unsigned v) { return __uint_as_float(v << 16); }
__device__ __forceinline__ float bfhi(unsigned v) { return __uint_as_float(v & 0xffff0000u); }
__device__ __forceinline__ unsigned packbf(float a, float b) {
  return (unsigned)f2bf(a) | ((unsigned)f2bf(b) << 16);
}

// ---------------------------------------------------------------------------
// x (fp32) -> bf16, 4 elements per thread
// ---------------------------------------------------------------------------
__global__ __launch_bounds__(256) void cvt_bf16_kernel(
    const float* __restrict__ X, unsigned short* __restrict__ Xb, int total4) {
  int i = blockIdx.x * 256 + threadIdx.x;
  if (i >= total4) return;
  float4 v = ((const float4*)X)[i];
  ushort4 o;
  o.x = f2bf(v.x); o.y = f2bf(v.y); o.z = f2bf(v.z); o.w = f2bf(v.w);
  ((ushort4*)Xb)[i] = o;
}

// ---------------------------------------------------------------------------
// Pack W[128 x C] (fp32, row-major) into MFMA B-fragment layout (bf16)
// ---------------------------------------------------------------------------
template <int C>
__global__ __launch_bounds__(256) void pack_w_kernel(
    const float* __restrict__ W, unsigned short* __restrict__ Bp) {
  const int total = (C / 16) * 4 * 64;
  int idx = blockIdx.x * 256 + threadIdx.x;
  if (idx >= total) return;
  int lane = idx & 63;
  int kc = (idx >> 6) & 3;
  int t = idx >> 8;
  int n = t * 16 + (lane & 15);
  int k0 = kc * 32 + (lane >> 4) * 8;
  unsigned short* o = Bp + (size_t)idx * 8;
#pragma unroll
  for (int j = 0; j < 8; j++) o[j] = f2bf(W[(size_t)(k0 + j) * C + n]);
}

// ---------------------------------------------------------------------------
// Merged transform: Ys = Xb@Ws + bs, Yd = Xb@Wd + bd, outputs packed bf16.
// ---------------------------------------------------------------------------
template <int NT>
__global__ __launch_bounds__(256) void mfma_xform2(
    const unsigned short* __restrict__ Xb,
    const unsigned short* __restrict__ BpS, const unsigned short* __restrict__ BpD,
    const float* __restrict__ bS, const float* __restrict__ bD,
    unsigned int* __restrict__ Ys, unsigned int* __restrict__ Yd, int M) {
  const int wave = threadIdx.x >> 6;
  const int lane = threadIdx.x & 63;
  const int row0 = blockIdx.x * 64 + wave * 16;
  const int m = lane & 15, q = lane >> 4;
  const int arow = min(row0 + m, M - 1);
  const unsigned short* aptr = Xb + (size_t)arow * 128 + q * 8;
  short8v a[4];
#pragma unroll
  for (int kc = 0; kc < 4; kc++) a[kc] = *(const short8v*)(aptr + kc * 32);
  float4v accS[NT], accD[NT];
#pragma unroll
  for (int t = 0; t < NT; t++) { accS[t] = (float4v)(0.f); accD[t] = (float4v)(0.f); }
#pragma unroll
  for (int kc = 0; kc < 4; kc++) {
#pragma unroll
    for (int t = 0; t < NT; t++) {
      short8v bs = *(const short8v*)(BpS + ((size_t)(t * 4 + kc) * 64 + lane) * 8);
      short8v bd = *(const short8v*)(BpD + ((size_t)(t * 4 + kc) * 64 + lane) * 8);
      accS[t] = __builtin_amdgcn_mfma_f32_16x16x32_bf16(a[kc], bs, accS[t], 0, 0, 0);
      accD[t] = __builtin_amdgcn_mfma_f32_16x16x32_bf16(a[kc], bd, accD[t], 0, 0, 0);
    }
  }
  const bool even = (m & 1) == 0;
#pragma unroll
  for (int t = 0; t < NT; t++) {
    const int col = t * 16 + m;
    const float bcS = bS[col], bcD = bD[col];
#pragma unroll
    for (int r = 0; r < 4; r++) {
      const int row = row0 + q * 4 + r;
      float vS = accS[t][r] + bcS;
      float vD = accD[t][r] + bcD;
      float pS = __shfl_xor(vS, 1);
      float pD = __shfl_xor(vD, 1);
      if (even && row < M) {
        size_t idx = (size_t)row * (NT * 8) + t * 8 + (m >> 1);
        Ys[idx] = packbf(vS, pS);
        Yd[idx] = packbf(vD, pD);
      }
    }
  }
}

// ---------------------------------------------------------------------------
// CSR build (self-loops INCLUDED): count=1 init, edge histogram,
// hierarchical scan, merged scatter (edges + self entries).
// ---------------------------------------------------------------------------
__global__ __launch_bounds__(256) void init_count(int* __restrict__ count, int n) {
  int i = blockIdx.x * 256 + threadIdx.x;
  if (i < n) count[i] = 1;
}

__global__ __launch_bounds__(256) void hist_kernel(
    const int* __restrict__ ei, int* __restrict__ count, int N, int E) {
  int e = blockIdx.x * 256 + threadIdx.x;
  if (e >= E) return;
  int d = ei[E + e];
  d = min(max(d, 0), N - 1);
  atomicAdd(count + d, 1);
}

__global__ __launch_bounds__(256) void scan_partial(
    const int* __restrict__ count, int* __restrict__ bsum, int n) {
  const int tid = threadIdx.x;
  const int base = blockIdx.x * 2048 + tid * 8;
  int s = 0;
#pragma unroll
  for (int j = 0; j < 8; j++) {
    int idx = base + j;
    if (idx < n) s += count[idx];
  }
#pragma unroll
  for (int off = 1; off < 64; off <<= 1) s += __shfl_xor(s, off);
  __shared__ int ws[4];
  if ((tid & 63) == 0) ws[tid >> 6] = s;
  __syncthreads();
  if (tid == 0) bsum[blockIdx.x] = ws[0] + ws[1] + ws[2] + ws[3];
}

__global__ __launch_bounds__(64) void scan_bsums(
    const int* __restrict__ bsum, int* __restrict__ bofs,
    int* __restrict__ row_ofs, int nblk, int n) {
  const int lane = threadIdx.x;
  int carry = 0;
  for (int b0 = 0; b0 < nblk; b0 += 64) {
    int i = b0 + lane;
    int v = (i < nblk) ? bsum[i] : 0;
    int incl = v;
#pragma unroll
    for (int off = 1; off < 64; off <<= 1) {
      int t = __shfl_up(incl, off);
      if (lane >= off) incl += t;
    }
    if (i < nblk) bofs[i] = carry + incl - v;
    carry += __shfl(incl, 63);
  }
  if (lane == 0) row_ofs[n] = carry;
}

__global__ __launch_bounds__(256) void scan_final(
    const int* __restrict__ count, const int* __restrict__ bofs,
    int* __restrict__ row_ofs, int* __restrict__ wofs, int n) {
  const int tid = threadIdx.x;
  const int lane = tid & 63;
  const int wid = tid >> 6;
  const int base = blockIdx.x * 2048 + tid * 8;
  int c[8];
  int s = 0;
#pragma unroll
  for (int j = 0; j < 8; j++) {
    int idx = base + j;
    c[j] = (idx < n) ? count[idx] : 0;
    s += c[j];
  }
  int incl = s;
#pragma unroll
  for (int off = 1; off < 64; off <<= 1) {
    int t = __shfl_up(incl, off);
    if (lane >= off) incl += t;
  }
  __shared__ int ws[4];
  if (lane == 63) ws[wid] = incl;
  __syncthreads();
  int wbase = 0;
  for (int w = 0; w < wid; w++) wbase += ws[w];
  int running = bofs[blockIdx.x] + wbase + incl - s;
#pragma unroll
  for (int j = 0; j < 8; j++) {
    int idx = base + j;
    if (idx < n) {
      row_ofs[idx] = running;
      wofs[idx] = running;
      running += c[j];
    }
  }
}

// edges then self-loops, one launch
__global__ __launch_bounds__(256) void scatter_all(
    const int* __restrict__ ei, int* __restrict__ wofs,
    int* __restrict__ src_sorted, int N, int E) {
  int e = blockIdx.x * 256 + threadIdx.x;
  if (e < E) {
    int s = ei[e], d = ei[E + e];
    s = min(max(s, 0), N - 1);
    d = min(max(d, 0), N - 1);
    int pos = atomicAdd(wofs + d, 1);
    src_sorted[pos] = s;
  } else if (e < E + N) {
    int i = e - E;
    int pos = atomicAdd(wofs + i, 1);
    src_sorted[pos] = i;
  }
}

// ---------------------------------------------------------------------------
// Layer-1 fused: one wave per dst node, 2 edges/iteration.
// Two 32-lane groups (g = lane>>5); lane l = lane&31 covers ch 4l..4l+3.
// Head h = l>>2 (4 lanes/head) -> 2-shfl reduce. Cross-group combine xor 32.
// ---------------------------------------------------------------------------
__global__ __launch_bounds__(256) void gat1_fused(
    const int* __restrict__ row_ofs, const int* __restrict__ src_sorted,
    const unsigned int* __restrict__ xsb, const unsigned int* __restrict__ xdb,
    const float* __restrict__ att, const float* __restrict__ bias,
    unsigned int* __restrict__ h1b, int N) {
  const int node = (int)((blockIdx.x * 256u + threadIdx.x) >> 6);
  const int lane = threadIdx.x & 63;
  const int l = lane & 31;
  if (node >= N) return;
  const float4 at = *(const float4*)(att + 4 * l);
  const uint2 xdp = *(const uint2*)(xdb + (size_t)node * 64 + 2 * l);
  const float xd0 = bflo(xdp.x), xd1 = bfhi(xdp.x);
  const float xd2 = bflo(xdp.y), xd3 = bfhi(xdp.y);
  float a0 = 0.f, a1 = 0.f, a2 = 0.f, a3 = 0.f, den = 0.f;
  const int b = row_ofs[node], eend = row_ofs[node + 1];  // >= 1 entries (self incl.)
  const int iters = (eend - b + 1) >> 1;
  int e = b + (lane >> 5);
  bool valid = e < eend;
  int s0 = valid ? src_sorted[e] : node;
  uint2 mp = *(const uint2*)(xsb + (size_t)s0 * 64 + 2 * l);
  for (int it = 0; it < iters; it++) {
    const uint2 cur = mp;
    const bool v = valid;
    e += 2;
    valid = e < eend;
    if (it + 1 < iters) {
      int sn = valid ? src_sorted[e] : node;
      mp = *(const uint2*)(xsb + (size_t)sn * 64 + 2 * l);
    }
    float m0 = bflo(cur.x), m1 = bfhi(cur.x);
    float m2 = bflo(cur.y), m3 = bfhi(cur.y);
    float p = lrelu(m0 + xd0) * at.x + lrelu(m1 + xd1) * at.y +
              lrelu(m2 + xd2) * at.z + lrelu(m3 + xd3) * at.w;
    p += __shfl_xor(p, 1);
    p += __shfl_xor(p, 2);
    float ex = v ? __expf(p) : 0.f;
    den += ex;
    a0 = fmaf(ex, m0, a0);
    a1 = fmaf(ex, m1, a1);
    a2 = fmaf(ex, m2, a2);
    a3 = fmaf(ex, m3, a3);
  }
  a0 += __shfl_xor(a0, 32);
  a1 += __shfl_xor(a1, 32);
  a2 += __shfl_xor(a2, 32);
  a3 += __shfl_xor(a3, 32);
  den += __shfl_xor(den, 32);
  const float inv = 1.f / den;
  const float4 bc = *(const float4*)(bias + 4 * l);
  float v0 = fmaf(a0, inv, bc.x);
  float v1 = fmaf(a1, inv, bc.y);
  float v2 = fmaf(a2, inv, bc.z);
  float v3 = fmaf(a3, inv, bc.w);
  v0 = v0 > 0.f ? v0 : __expf(v0) - 1.f;
  v1 = v1 > 0.f ? v1 : __expf(v1) - 1.f;
  v2 = v2 > 0.f ? v2 : __expf(v2) - 1.f;
  v3 = v3 > 0.f ? v3 : __expf(v3) - 1.f;
  if (lane < 32) {
    *(uint2*)(h1b + (size_t)node * 64 + 2 * l) =
        make_uint2(packbf(v0, v1), packbf(v2, v3));
  }
}

// ---------------------------------------------------------------------------
// Layer-2 fused: one wave per dst node, 8 edges/iteration.
// Eight 8-lane groups (g = lane>>3); lane l = lane&7 covers ch 4l..4l+3.
// Edge-dot reduce: 3 shfl; cross-group combine xor 8,16,32; + log_softmax.
// ---------------------------------------------------------------------------
__global__ __launch_bounds__(256) void gat2_fused(
    const int* __restrict__ row_ofs, const int* __restrict__ src_sorted,
    const unsigned int* __restrict__ xsb, const unsigned int* __restrict__ xdb,
    const float* __restrict__ att, const float* __restrict__ bias,
    float* __restrict__ out, int N) {
  const int node = (int)((blockIdx.x * 256u + threadIdx.x) >> 6);
  const int lane = threadIdx.x & 63;
  const int l = lane & 7;
  if (node >= N) return;
  const float4 at = *(const float4*)(att + 4 * l);
  const uint2 xdp = *(const uint2*)(xdb + (size_t)node * 16 + 2 * l);
  const float xd0 = bflo(xdp.x), xd1 = bfhi(xdp.x);
  const float xd2 = bflo(xdp.y), xd3 = bfhi(xdp.y);
  float a0 = 0.f, a1 = 0.f, a2 = 0.f, a3 = 0.f, den = 0.f;
  const int b = row_ofs[node], eend = row_ofs[node + 1];
  const int iters = (eend - b + 7) >> 3;
  int e = b + (lane >> 3);
  bool valid = e < eend;
  int s0 = valid ? src_sorted[e] : node;
  uint2 mp = *(const uint2*)(xsb + (size_t)s0 * 16 + 2 * l);
  for (int it = 0; it < iters; it++) {
    const uint2 cur = mp;
    const bool v = valid;
    e += 8;
    valid = e < eend;
    if (it + 1 < iters) {
      int sn = valid ? src_sorted[e] : node;
      mp = *(const uint2*)(xsb + (size_t)sn * 16 + 2 * l);
    }
    float m0 = bflo(cur.x), m1 = bfhi(cur.x);
    float m2 = bflo(cur.y), m3 = bfhi(cur.y);
    float p = lrelu(m0 + xd0) * at.x + lrelu(m1 + xd1) * at.y +
              lrelu(m2 + xd2) * at.z + lrelu(m3 + xd3) * at.w;
    p += __shfl_xor(p, 1);
    p += __shfl_xor(p, 2);
    p += __shfl_xor(p, 4);
    float ex = v ? __expf(p) : 0.f;
    den += ex;
    a0 = fmaf(ex, m0, a0);
    a1 = fmaf(ex, m1, a1);
    a2 = fmaf(ex, m2, a2);
    a3 = fmaf(ex, m3, a3);
  }
#pragma unroll
  for (int off = 8; off < 64; off <<= 1) {
    a0 += __shfl_xor(a0, off);
    a1 += __shfl_xor(a1, off);
    a2 += __shfl_xor(a2, off);
    a3 += __shfl_xor(a3, off);
    den += __shfl_xor(den, off);
  }
  const float inv = 1.f / den;
  const float4 bc = *(const float4*)(bias + 4 * l);
  float v0 = fmaf(a0, inv, bc.x);
  float v1 = fmaf(a1, inv, bc.y);
  float v2 = fmaf(a2, inv, bc.z);
  float v3 = fmaf(a3, inv, bc.w);
  // log_softmax over 32 channels (4 local x 8 lanes)
  float mx = fmaxf(fmaxf(v0, v1), fmaxf(v2, v3));
  mx = fmaxf(mx, __shfl_xor(mx, 1));
  mx = fmaxf(mx, __shfl_xor(mx, 2));
  mx = fmaxf(mx, __shfl_xor(mx, 4));
  float sum = __expf(v0 - mx) + __expf(v1 - mx) + __expf(v2 - mx) + __expf(v3 - mx);
  sum += __shfl_xor(sum, 1);
  sum += __shfl_xor(sum, 2);
  sum += __shfl_xor(sum, 4);
  const float lse = mx + __logf(sum);
  if (lane < 8) {
    *(float4*)(out + (size_t)node * 32 + 4 * l) =
        make_float4(v0 - lse, v1 - lse, v2 - lse, v3 - lse);
  }
}

extern "C" void kernel_launch(void* const* d_in, const int* in_sizes, int n_in,
                              void* d_out, int out_size, void* d_ws, size_t ws_size,
                              hipStream_t stream) {
  const float* x = (const float*)d_in[0];
  const int* ei = (const int*)d_in[1];
  const float* W1s = (const float*)d_in[2];
  const float* W1d = (const float*)d_in[3];
  const float* b1s = (const float*)d_in[4];
  const float* b1d = (const float*)d_in[5];
  const float* att1 = (const float*)d_in[6];
  const float* bias1 = (const float*)d_in[7];
  const float* W2s = (const float*)d_in[8];
  const float* W2d = (const float*)d_in[9];
  const float* b2s = (const float*)d_in[10];
  const float* b2d = (const float*)d_in[11];
  const float* att2 = (const float*)d_in[12];
  const float* bias2 = (const float*)d_in[13];
  float* out = (float*)d_out;

  const int N = in_sizes[0] / 128;
  const int E = in_sizes[1] / 2;

  char* p = (char*)d_ws;
  auto alloc = [&](size_t bytes) { char* r = p; p += (bytes + 63) & ~63ull; return r; };
  unsigned int* xs1b = (unsigned int*)alloc((size_t)N * 64 * 4);
  unsigned int* xd1b = (unsigned int*)alloc((size_t)N * 64 * 4);
  unsigned int* xs2b = (unsigned int*)alloc((size_t)N * 16 * 4);
  unsigned int* xd2b = (unsigned int*)alloc((size_t)N * 16 * 4);
  unsigned short* xb = (unsigned short*)alloc((size_t)N * 128 * 2);
  unsigned int* h1b = (unsigned int*)alloc((size_t)N * 64 * 4);
  unsigned short* Bp1s = (unsigned short*)alloc(8 * 4 * 64 * 8 * 2);
  unsigned short* Bp1d = (unsigned short*)alloc(8 * 4 * 64 * 8 * 2);
  unsigned short* Bp2s = (unsigned short*)alloc(2 * 4 * 64 * 8 * 2);
  unsigned short* Bp2d = (unsigned short*)alloc(2 * 4 * 64 * 8 * 2);
  int* count = (int*)alloc((size_t)N * 4);
  int* row_ofs = (int*)alloc((size_t)(N + 1) * 4);
  int* wofs = (int*)alloc((size_t)(N + 1) * 4);
  int* src_sorted = (int*)alloc((size_t)(E + N) * 4);
  const int nsblk = (N + 2047) / 2048;
  int* bsum = (int*)alloc((size_t)nsblk * 4);
  int* bofs = (int*)alloc((size_t)nsblk * 4);

  const int total4 = N * 128 / 4;
  cvt_bf16_kernel<<<(total4 + 255) / 256, 256, 0, stream>>>(x, xb, total4);
  pack_w_kernel<128><<<8, 256, 0, stream>>>(W1s, Bp1s);
  pack_w_kernel<128><<<8, 256, 0, stream>>>(W1d, Bp1d);
  pack_w_kernel<32><<<2, 256, 0, stream>>>(W2s, Bp2s);
  pack_w_kernel<32><<<2, 256, 0, stream>>>(W2d, Bp2d);

  const int nblk = (N + 255) / 256;
  init_count<<<nblk, 256, 0, stream>>>(count, N);
  hist_kernel<<<(E + 255) / 256, 256, 0, stream>>>(ei, count, N, E);
  scan_partial<<<nsblk, 256, 0, stream>>>(count, bsum, N);
  scan_bsums<<<1, 64, 0, stream>>>(bsum, bofs, row_ofs, nsblk, N);
  scan_final<<<nsblk, 256, 0, stream>>>(count, bofs, row_ofs, wofs, N);
  scatter_all<<<(E + N + 255) / 256, 256, 0, stream>>>(ei, wofs, src_sorted, N, E);

  const int xblocks = (N + 63) / 64;
  mfma_xform2<8><<<xblocks, 256, 0, stream>>>(xb, Bp1s, Bp1d, b1s, b1d, xs1b, xd1b, N);

  gat1_fused<<<(N + 3) / 4, 256, 0, stream>>>(row_ofs, src_sorted, xs1b, xd1b,
                                              att1, bias1, h1b, N);

  mfma_xform2<2><<<xblocks, 256, 0, stream>>>((const unsigned short*)h1b, Bp2s, Bp2d,
                                              b2s, b2d, xs2b, xd2b, N);

  gat2_fused<<<(N + 3) / 4, 256, 0, stream>>>(row_ofs, src_sorted, xs2b, xd2b,
                                              att2, bias2, out, N);
}

// Round 8
// 246.969 us; speedup vs baseline: 3.2838x; 1.2742x over previous
//
#include <hip/hip_runtime.h>
#include <math.h>

#define NEG_SLOPE 0.2f

typedef __attribute__((ext_vector_type(8))) short short8v;
typedef __attribute__((ext_vector_type(4))) float float4v;

__device__ __forceinline__ float lrelu(float x) { return fmaxf(x, NEG_SLOPE * x); }

__device__ __forceinline__ unsigned short f2bf(float f) {
  unsigned u = __float_as_uint(f);
  u += 0x7fffu + ((u >> 16) & 1u);
  return (unsigned short)(u >> 16);
}
__device__ __forceinline__ float bflo(unsigned v) { return __uint_as_float(v << 16); }
__device__ __forceinline__ float bfhi(unsigned v) { return __uint_as_float(v & 0xffff0000u); }
__device__ __forceinline__ unsigned packbf(float a, float b) {
  return (unsigned)f2bf(a) | ((unsigned)f2bf(b) << 16);
}

// 256-wide block exclusive scan; all 256 threads must call. ws: >=8 ints LDS.
__device__ __forceinline__ int block_scan256(int v, int tid, int* ws) {
  const int lane = tid & 63, w = tid >> 6;
  int incl = v;
#pragma unroll
  for (int off = 1; off < 64; off <<= 1) {
    int t = __shfl_up(incl, off);
    if (lane >= off) incl += t;
  }
  if (lane == 63) ws[w] = incl;
  __syncthreads();
  if (tid == 0) {
    int s = 0;
#pragma unroll
    for (int i = 0; i < 4; i++) { int t = ws[i]; ws[4 + i] = s; s += t; }
  }
  __syncthreads();
  return incl - v + ws[4 + w];
}

// ---------------------------------------------------------------------------
// x (fp32) -> bf16, 4 elements per thread
// ---------------------------------------------------------------------------
__global__ __launch_bounds__(256) void cvt_bf16_kernel(
    const float* __restrict__ X, unsigned short* __restrict__ Xb, int total4) {
  int i = blockIdx.x * 256 + threadIdx.x;
  if (i >= total4) return;
  float4 v = ((const float4*)X)[i];
  ushort4 o;
  o.x = f2bf(v.x); o.y = f2bf(v.y); o.z = f2bf(v.z); o.w = f2bf(v.w);
  ((ushort4*)Xb)[i] = o;
}

// ---------------------------------------------------------------------------
// Pack all 4 weight matrices into MFMA B-fragment layout (bf16), one launch.
// blocks 0-7: W1s, 8-15: W1d, 16-17: W2s, 18-19: W2d.
// ---------------------------------------------------------------------------
__global__ __launch_bounds__(256) void pack_all(
    const float* __restrict__ W1s, const float* __restrict__ W1d,
    const float* __restrict__ W2s, const float* __restrict__ W2d,
    unsigned short* __restrict__ B1s, unsigned short* __restrict__ B1d,
    unsigned short* __restrict__ B2s, unsigned short* __restrict__ B2d) {
  int blk = blockIdx.x;
  const float* W; unsigned short* Bp; int C, base;
  if (blk < 8)       { W = W1s; Bp = B1s; C = 128; base = blk; }
  else if (blk < 16) { W = W1d; Bp = B1d; C = 128; base = blk - 8; }
  else if (blk < 18) { W = W2s; Bp = B2s; C = 32;  base = blk - 16; }
  else               { W = W2d; Bp = B2d; C = 32;  base = blk - 18; }
  int idx = base * 256 + threadIdx.x;
  int total = (C / 16) * 4 * 64;
  if (idx >= total) return;
  int lane = idx & 63;
  int kc = (idx >> 6) & 3;
  int t = idx >> 8;
  int n = t * 16 + (lane & 15);
  int k0 = kc * 32 + (lane >> 4) * 8;
  unsigned short* o = Bp + (size_t)idx * 8;
#pragma unroll
  for (int j = 0; j < 8; j++) o[j] = f2bf(W[(size_t)(k0 + j) * C + n]);
}

// ---------------------------------------------------------------------------
// Merged transform: Ys = Xb@Ws + bs, Yd = Xb@Wd + bd, outputs packed bf16.
// ---------------------------------------------------------------------------
template <int NT>
__global__ __launch_bounds__(256) void mfma_xform2(
    const unsigned short* __restrict__ Xb,
    const unsigned short* __restrict__ BpS, const unsigned short* __restrict__ BpD,
    const float* __restrict__ bS, const float* __restrict__ bD,
    unsigned int* __restrict__ Ys, unsigned int* __restrict__ Yd, int M) {
  const int wave = threadIdx.x >> 6;
  const int lane = threadIdx.x & 63;
  const int row0 = blockIdx.x * 64 + wave * 16;
  const int m = lane & 15, q = lane >> 4;
  const int arow = min(row0 + m, M - 1);
  const unsigned short* aptr = Xb + (size_t)arow * 128 + q * 8;
  short8v a[4];
#pragma unroll
  for (int kc = 0; kc < 4; kc++) a[kc] = *(const short8v*)(aptr + kc * 32);
  float4v accS[NT], accD[NT];
#pragma unroll
  for (int t = 0; t < NT; t++) { accS[t] = (float4v)(0.f); accD[t] = (float4v)(0.f); }
#pragma unroll
  for (int kc = 0; kc < 4; kc++) {
#pragma unroll
    for (int t = 0; t < NT; t++) {
      short8v bs = *(const short8v*)(BpS + ((size_t)(t * 4 + kc) * 64 + lane) * 8);
      short8v bd = *(const short8v*)(BpD + ((size_t)(t * 4 + kc) * 64 + lane) * 8);
      accS[t] = __builtin_amdgcn_mfma_f32_16x16x32_bf16(a[kc], bs, accS[t], 0, 0, 0);
      accD[t] = __builtin_amdgcn_mfma_f32_16x16x32_bf16(a[kc], bd, accD[t], 0, 0, 0);
    }
  }
  const bool even = (m & 1) == 0;
#pragma unroll
  for (int t = 0; t < NT; t++) {
    const int col = t * 16 + m;
    const float bcS = bS[col], bcD = bD[col];
#pragma unroll
    for (int r = 0; r < 4; r++) {
      const int row = row0 + q * 4 + r;
      float vS = accS[t][r] + bcS;
      float vD = accD[t][r] + bcD;
      float pS = __shfl_xor(vS, 1);
      float pD = __shfl_xor(vD, 1);
      if (even && row < M) {
        size_t idx = (size_t)row * (NT * 8) + t * 8 + (m >> 1);
        Ys[idx] = packbf(vS, pS);
        Yd[idx] = packbf(vD, pD);
      }
    }
  }
}

// ---------------------------------------------------------------------------
// CSR build, two-level counting sort. Buckets of 256 dst values.
// ---------------------------------------------------------------------------
// A0: per-bucket edge histogram (LDS-aggregated).
__global__ __launch_bounds__(256) void bucket_hist(
    const int* __restrict__ ei, int* __restrict__ bhist, int N, int E, int NB) {
  __shared__ int cnt[256];
  const int tid = threadIdx.x;
  cnt[tid] = 0;
  __syncthreads();
  const int base = blockIdx.x * 4096;
  const int vn = min(4096, E - base);
#pragma unroll 4
  for (int j = 0; j < 16; j++) {
    int i = j * 256 + tid;
    if (i < vn) {
      int d = ei[E + base + i];
      d = min(max(d, 0), N - 1);
      atomicAdd(&cnt[d >> 8], 1);
    }
  }
  __syncthreads();
  if (tid < NB && cnt[tid]) atomicAdd(&bhist[tid], cnt[tid]);
}

// A-scan: one block; bbase = exclusive scan of bhist; bcur = bbase.
__global__ __launch_bounds__(256) void bucket_scan(
    const int* __restrict__ bhist, int* __restrict__ bbase,
    int* __restrict__ bcur, int NB) {
  __shared__ int ws[8];
  const int tid = threadIdx.x;
  int v = (tid < NB) ? bhist[tid] : 0;
  int excl = block_scan256(v, tid, ws);
  if (tid <= NB) bbase[tid] = excl;
  if (tid < NB) bcur[tid] = excl;
}

// A1: block-local counting sort of 4096 edges by bucket, coalesced run copy.
// pairs[i] = src | (dstLow8 << 16).
__global__ __launch_bounds__(256) void bucket_sort(
    const int* __restrict__ ei, int* __restrict__ bcur,
    unsigned int* __restrict__ pairs, int N, int E, int NB) {
  __shared__ int cnt[256];
  __shared__ int offs[256];
  __shared__ int gbase[256];
  __shared__ int lcur[256];
  __shared__ int ws[8];
  __shared__ unsigned int packed_s[4096];
  __shared__ unsigned char bucket_of[4096];
  const int tid = threadIdx.x;
  cnt[tid] = 0;
  __syncthreads();
  const int base = blockIdx.x * 4096;
  const int vn = min(4096, E - base);
  // pass 1: count buckets
#pragma unroll 4
  for (int j = 0; j < 16; j++) {
    int i = j * 256 + tid;
    if (i < vn) {
      int d = ei[E + base + i];
      d = min(max(d, 0), N - 1);
      atomicAdd(&cnt[d >> 8], 1);
    }
  }
  __syncthreads();
  int excl = block_scan256(cnt[tid], tid, ws);
  offs[tid] = excl;
  lcur[tid] = excl;
  if (tid < NB && cnt[tid]) gbase[tid] = atomicAdd(&bcur[tid], cnt[tid]);
  __syncthreads();
  // pass 2: scatter into LDS by bucket
#pragma unroll 4
  for (int j = 0; j < 16; j++) {
    int i = j * 256 + tid;
    if (i < vn) {
      int s = ei[base + i];
      int d = ei[E + base + i];
      s = min(max(s, 0), N - 1);
      d = min(max(d, 0), N - 1);
      int b = d >> 8;
      int slot = atomicAdd(&lcur[b], 1);
      packed_s[slot] = (unsigned)s | ((unsigned)(d & 255) << 16);
      bucket_of[slot] = (unsigned char)b;
    }
  }
  __syncthreads();
  // coalesced-ish copy out: runs per bucket are contiguous
  for (int i = tid; i < vn; i += 256) {
    int b = bucket_of[i];
    pairs[gbase[b] + (i - offs[b])] = packed_s[i];
  }
}

// B: one block per bucket: fine counting sort by dst, self-loops included,
// writes row_ofs (sequential) + src_sorted (L2-local scatter).
__global__ __launch_bounds__(256) void csr_fine(
    const unsigned int* __restrict__ pairs, const int* __restrict__ bbase,
    int* __restrict__ row_ofs, int* __restrict__ src_sorted, int N, int E, int NB) {
  __shared__ int cnt[256];
  __shared__ int cursor[256];
  __shared__ int ws[8];
  const int tid = threadIdx.x;
  const int b = blockIdx.x;
  const int d0 = b << 8;
  const int nd = min(256, N - d0);
  const int pbase = bbase[b];
  const int pcnt = bbase[b + 1] - pbase;
  const int row_base = pbase + d0;  // all prior buckets are full (256 selfs each)
  cnt[tid] = (tid < nd) ? 1 : 0;   // self-loop
  __syncthreads();
  for (int i = tid; i < pcnt; i += 256) {
    unsigned p = pairs[pbase + i];
    atomicAdd(&cnt[(p >> 16) & 255], 1);
  }
  __syncthreads();
  int excl = block_scan256(cnt[tid], tid, ws);
  if (tid < nd) {
    row_ofs[d0 + tid] = row_base + excl;
    src_sorted[row_base + excl] = d0 + tid;  // self entry first in segment
    cursor[tid] = excl + 1;
  }
  if (b == NB - 1 && tid == 0) row_ofs[N] = E + N;
  __syncthreads();
  for (int i = tid; i < pcnt; i += 256) {
    unsigned p = pairs[pbase + i];
    int dl = (p >> 16) & 255;
    int slot = atomicAdd(&cursor[dl], 1);
    src_sorted[row_base + slot] = (int)(p & 0xffffu);
  }
}

// ---------------------------------------------------------------------------
// Layer-1 fused: one wave per dst node, 2 edges/iteration.
// ---------------------------------------------------------------------------
__global__ __launch_bounds__(256) void gat1_fused(
    const int* __restrict__ row_ofs, const int* __restrict__ src_sorted,
    const unsigned int* __restrict__ xsb, const unsigned int* __restrict__ xdb,
    const float* __restrict__ att, const float* __restrict__ bias,
    unsigned int* __restrict__ h1b, int N) {
  const int node = (int)((blockIdx.x * 256u + threadIdx.x) >> 6);
  const int lane = threadIdx.x & 63;
  const int l = lane & 31;
  if (node >= N) return;
  const float4 at = *(const float4*)(att + 4 * l);
  const uint2 xdp = *(const uint2*)(xdb + (size_t)node * 64 + 2 * l);
  const float xd0 = bflo(xdp.x), xd1 = bfhi(xdp.x);
  const float xd2 = bflo(xdp.y), xd3 = bfhi(xdp.y);
  float a0 = 0.f, a1 = 0.f, a2 = 0.f, a3 = 0.f, den = 0.f;
  const int b = row_ofs[node], eend = row_ofs[node + 1];
  const int iters = (eend - b + 1) >> 1;
  int e = b + (lane >> 5);
  bool valid = e < eend;
  int s0 = valid ? src_sorted[e] : node;
  uint2 mp = *(const uint2*)(xsb + (size_t)s0 * 64 + 2 * l);
  for (int it = 0; it < iters; it++) {
    const uint2 cur = mp;
    const bool v = valid;
    e += 2;
    valid = e < eend;
    if (it + 1 < iters) {
      int sn = valid ? src_sorted[e] : node;
      mp = *(const uint2*)(xsb + (size_t)sn * 64 + 2 * l);
    }
    float m0 = bflo(cur.x), m1 = bfhi(cur.x);
    float m2 = bflo(cur.y), m3 = bfhi(cur.y);
    float p = lrelu(m0 + xd0) * at.x + lrelu(m1 + xd1) * at.y +
              lrelu(m2 + xd2) * at.z + lrelu(m3 + xd3) * at.w;
    p += __shfl_xor(p, 1);
    p += __shfl_xor(p, 2);
    float ex = v ? __expf(p) : 0.f;
    den += ex;
    a0 = fmaf(ex, m0, a0);
    a1 = fmaf(ex, m1, a1);
    a2 = fmaf(ex, m2, a2);
    a3 = fmaf(ex, m3, a3);
  }
  a0 += __shfl_xor(a0, 32);
  a1 += __shfl_xor(a1, 32);
  a2 += __shfl_xor(a2, 32);
  a3 += __shfl_xor(a3, 32);
  den += __shfl_xor(den, 32);
  const float inv = 1.f / den;
  const float4 bc = *(const float4*)(bias + 4 * l);
  float v0 = fmaf(a0, inv, bc.x);
  float v1 = fmaf(a1, inv, bc.y);
  float v2 = fmaf(a2, inv, bc.z);
  float v3 = fmaf(a3, inv, bc.w);
  v0 = v0 > 0.f ? v0 : __expf(v0) - 1.f;
  v1 = v1 > 0.f ? v1 : __expf(v1) - 1.f;
  v2 = v2 > 0.f ? v2 : __expf(v2) - 1.f;
  v3 = v3 > 0.f ? v3 : __expf(v3) - 1.f;
  if (lane < 32) {
    *(uint2*)(h1b + (size_t)node * 64 + 2 * l) =
        make_uint2(packbf(v0, v1), packbf(v2, v3));
  }
}

// ---------------------------------------------------------------------------
// Layer-2 fused: one wave per dst node, 8 edges/iteration + log_softmax.
// ---------------------------------------------------------------------------
__global__ __launch_bounds__(256) void gat2_fused(
    const int* __restrict__ row_ofs, const int* __restrict__ src_sorted,
    const unsigned int* __restrict__ xsb, const unsigned int* __restrict__ xdb,
    const float* __restrict__ att, const float* __restrict__ bias,
    float* __restrict__ out, int N) {
  const int node = (int)((blockIdx.x * 256u + threadIdx.x) >> 6);
  const int lane = threadIdx.x & 63;
  const int l = lane & 7;
  if (node >= N) return;
  const float4 at = *(const float4*)(att + 4 * l);
  const uint2 xdp = *(const uint2*)(xdb + (size_t)node * 16 + 2 * l);
  const float xd0 = bflo(xdp.x), xd1 = bfhi(xdp.x);
  const float xd2 = bflo(xdp.y), xd3 = bfhi(xdp.y);
  float a0 = 0.f, a1 = 0.f, a2 = 0.f, a3 = 0.f, den = 0.f;
  const int b = row_ofs[node], eend = row_ofs[node + 1];
  const int iters = (eend - b + 7) >> 3;
  int e = b + (lane >> 3);
  bool valid = e < eend;
  int s0 = valid ? src_sorted[e] : node;
  uint2 mp = *(const uint2*)(xsb + (size_t)s0 * 16 + 2 * l);
  for (int it = 0; it < iters; it++) {
    const uint2 cur = mp;
    const bool v = valid;
    e += 8;
    valid = e < eend;
    if (it + 1 < iters) {
      int sn = valid ? src_sorted[e] : node;
      mp = *(const uint2*)(xsb + (size_t)sn * 16 + 2 * l);
    }
    float m0 = bflo(cur.x), m1 = bfhi(cur.x);
    float m2 = bflo(cur.y), m3 = bfhi(cur.y);
    float p = lrelu(m0 + xd0) * at.x + lrelu(m1 + xd1) * at.y +
              lrelu(m2 + xd2) * at.z + lrelu(m3 + xd3) * at.w;
    p += __shfl_xor(p, 1);
    p += __shfl_xor(p, 2);
    p += __shfl_xor(p, 4);
    float ex = v ? __expf(p) : 0.f;
    den += ex;
    a0 = fmaf(ex, m0, a0);
    a1 = fmaf(ex, m1, a1);
    a2 = fmaf(ex, m2, a2);
    a3 = fmaf(ex, m3, a3);
  }
#pragma unroll
  for (int off = 8; off < 64; off <<= 1) {
    a0 += __shfl_xor(a0, off);
    a1 += __shfl_xor(a1, off);
    a2 += __shfl_xor(a2, off);
    a3 += __shfl_xor(a3, off);
    den += __shfl_xor(den, off);
  }
  const float inv = 1.f / den;
  const float4 bc = *(const float4*)(bias + 4 * l);
  float v0 = fmaf(a0, inv, bc.x);
  float v1 = fmaf(a1, inv, bc.y);
  float v2 = fmaf(a2, inv, bc.z);
  float v3 = fmaf(a3, inv, bc.w);
  float mx = fmaxf(fmaxf(v0, v1), fmaxf(v2, v3));
  mx = fmaxf(mx, __shfl_xor(mx, 1));
  mx = fmaxf(mx, __shfl_xor(mx, 2));
  mx = fmaxf(mx, __shfl_xor(mx, 4));
  float sum = __expf(v0 - mx) + __expf(v1 - mx) + __expf(v2 - mx) + __expf(v3 - mx);
  sum += __shfl_xor(sum, 1);
  sum += __shfl_xor(sum, 2);
  sum += __shfl_xor(sum, 4);
  const float lse = mx + __logf(sum);
  if (lane < 8) {
    *(float4*)(out + (size_t)node * 32 + 4 * l) =
        make_float4(v0 - lse, v1 - lse, v2 - lse, v3 - lse);
  }
}

extern "C" void kernel_launch(void* const* d_in, const int* in_sizes, int n_in,
                              void* d_out, int out_size, void* d_ws, size_t ws_size,
                              hipStream_t stream) {
  const float* x = (const float*)d_in[0];
  const int* ei = (const int*)d_in[1];
  const float* W1s = (const float*)d_in[2];
  const float* W1d = (const float*)d_in[3];
  const float* b1s = (const float*)d_in[4];
  const float* b1d = (const float*)d_in[5];
  const float* att1 = (const float*)d_in[6];
  const float* bias1 = (const float*)d_in[7];
  const float* W2s = (const float*)d_in[8];
  const float* W2d = (const float*)d_in[9];
  const float* b2s = (const float*)d_in[10];
  const float* b2d = (const float*)d_in[11];
  const float* att2 = (const float*)d_in[12];
  const float* bias2 = (const float*)d_in[13];
  float* out = (float*)d_out;

  const int N = in_sizes[0] / 128;
  const int E = in_sizes[1] / 2;
  const int NB = (N + 255) >> 8;  // buckets of 256 dst (requires N <= 65536)

  char* p = (char*)d_ws;
  auto alloc = [&](size_t bytes) { char* r = p; p += (bytes + 63) & ~63ull; return r; };
  unsigned int* xs1b = (unsigned int*)alloc((size_t)N * 64 * 4);
  unsigned int* xd1b = (unsigned int*)alloc((size_t)N * 64 * 4);
  unsigned int* xs2b = (unsigned int*)alloc((size_t)N * 16 * 4);
  unsigned int* xd2b = (unsigned int*)alloc((size_t)N * 16 * 4);
  unsigned short* xb = (unsigned short*)alloc((size_t)N * 128 * 2);
  unsigned int* h1b = (unsigned int*)alloc((size_t)N * 64 * 4);
  unsigned short* Bp1s = (unsigned short*)alloc(8 * 4 * 64 * 8 * 2);
  unsigned short* Bp1d = (unsigned short*)alloc(8 * 4 * 64 * 8 * 2);
  unsigned short* Bp2s = (unsigned short*)alloc(2 * 4 * 64 * 8 * 2);
  unsigned short* Bp2d = (unsigned short*)alloc(2 * 4 * 64 * 8 * 2);
  int* bhist = (int*)alloc((size_t)NB * 4);
  int* bbase = (int*)alloc((size_t)(NB + 1) * 4);
  int* bcur = (int*)alloc((size_t)NB * 4);
  unsigned int* pairs = (unsigned int*)alloc((size_t)E * 4);
  int* row_ofs = (int*)alloc((size_t)(N + 1) * 4);
  int* src_sorted = (int*)alloc((size_t)(E + N) * 4);

  hipMemsetAsync(bhist, 0, (size_t)NB * sizeof(int), stream);

  const int total4 = N * 128 / 4;
  cvt_bf16_kernel<<<(total4 + 255) / 256, 256, 0, stream>>>(x, xb, total4);
  pack_all<<<20, 256, 0, stream>>>(W1s, W1d, W2s, W2d, Bp1s, Bp1d, Bp2s, Bp2d);

  const int nA = (E + 4095) / 4096;
  bucket_hist<<<nA, 256, 0, stream>>>(ei, bhist, N, E, NB);
  bucket_scan<<<1, 256, 0, stream>>>(bhist, bbase, bcur, NB);
  bucket_sort<<<nA, 256, 0, stream>>>(ei, bcur, pairs, N, E, NB);
  csr_fine<<<NB, 256, 0, stream>>>(pairs, bbase, row_ofs, src_sorted, N, E, NB);

  const int xblocks = (N + 63) / 64;
  mfma_xform2<8><<<xblocks, 256, 0, stream>>>(xb, Bp1s, Bp1d, b1s, b1d, xs1b, xd1b, N);

  gat1_fused<<<(N + 3) / 4, 256, 0, stream>>>(row_ofs, src_sorted, xs1b, xd1b,
                                              att1, bias1, h1b, N);

  mfma_xform2<2><<<xblocks, 256, 0, stream>>>((const unsigned short*)h1b, Bp2s, Bp2d,
                                              b2s, b2d, xs2b, xd2b, N);

  gat2_fused<<<(N + 3) / 4, 256, 0, stream>>>(row_ofs, src_sorted, xs2b, xd2b,
                                              att2, bias2, out, N);
}

// Round 9
// 235.364 us; speedup vs baseline: 3.4457x; 1.0493x over previous
//
#include <hip/hip_runtime.h>
#include <math.h>

#define NEG_SLOPE 0.2f

typedef __attribute__((ext_vector_type(8))) short short8v;
typedef __attribute__((ext_vector_type(4))) float float4v;
typedef __attribute__((ext_vector_type(2))) float float2v;

__device__ __forceinline__ float lrelu(float x) { return fmaxf(x, NEG_SLOPE * x); }

__device__ __forceinline__ unsigned short f2bf(float f) {
  unsigned u = __float_as_uint(f);
  u += 0x7fffu + ((u >> 16) & 1u);
  return (unsigned short)(u >> 16);
}
__device__ __forceinline__ float bflo(unsigned v) { return __uint_as_float(v << 16); }
__device__ __forceinline__ float bfhi(unsigned v) { return __uint_as_float(v & 0xffff0000u); }
__device__ __forceinline__ unsigned packbf(float a, float b) {
  return (unsigned)f2bf(a) | ((unsigned)f2bf(b) << 16);
}
__device__ __forceinline__ float2v unpack2(unsigned u) {
  float2v r; r.x = bflo(u); r.y = bfhi(u); return r;
}

// 256-wide block exclusive scan; all 256 threads must call. ws: >=8 ints LDS.
__device__ __forceinline__ int block_scan256(int v, int tid, int* ws) {
  const int lane = tid & 63, w = tid >> 6;
  int incl = v;
#pragma unroll
  for (int off = 1; off < 64; off <<= 1) {
    int t = __shfl_up(incl, off);
    if (lane >= off) incl += t;
  }
  if (lane == 63) ws[w] = incl;
  __syncthreads();
  if (tid == 0) {
    int s = 0;
#pragma unroll
    for (int i = 0; i < 4; i++) { int t = ws[i]; ws[4 + i] = s; s += t; }
  }
  __syncthreads();
  return incl - v + ws[4 + w];
}

// ---------------------------------------------------------------------------
// x (fp32) -> bf16, 4 elements per thread
// ---------------------------------------------------------------------------
__global__ __launch_bounds__(256) void cvt_bf16_kernel(
    const float* __restrict__ X, unsigned short* __restrict__ Xb, int total4) {
  int i = blockIdx.x * 256 + threadIdx.x;
  if (i >= total4) return;
  float4 v = ((const float4*)X)[i];
  ushort4 o;
  o.x = f2bf(v.x); o.y = f2bf(v.y); o.z = f2bf(v.z); o.w = f2bf(v.w);
  ((ushort4*)Xb)[i] = o;
}

// ---------------------------------------------------------------------------
// Pack all 4 weight matrices into MFMA B-fragment layout (bf16), one launch.
// ---------------------------------------------------------------------------
__global__ __launch_bounds__(256) void pack_all(
    const float* __restrict__ W1s, const float* __restrict__ W1d,
    const float* __restrict__ W2s, const float* __restrict__ W2d,
    unsigned short* __restrict__ B1s, unsigned short* __restrict__ B1d,
    unsigned short* __restrict__ B2s, unsigned short* __restrict__ B2d) {
  int blk = blockIdx.x;
  const float* W; unsigned short* Bp; int C, base;
  if (blk < 8)       { W = W1s; Bp = B1s; C = 128; base = blk; }
  else if (blk < 16) { W = W1d; Bp = B1d; C = 128; base = blk - 8; }
  else if (blk < 18) { W = W2s; Bp = B2s; C = 32;  base = blk - 16; }
  else               { W = W2d; Bp = B2d; C = 32;  base = blk - 18; }
  int idx = base * 256 + threadIdx.x;
  int total = (C / 16) * 4 * 64;
  if (idx >= total) return;
  int lane = idx & 63;
  int kc = (idx >> 6) & 3;
  int t = idx >> 8;
  int n = t * 16 + (lane & 15);
  int k0 = kc * 32 + (lane >> 4) * 8;
  unsigned short* o = Bp + (size_t)idx * 8;
#pragma unroll
  for (int j = 0; j < 8; j++) o[j] = f2bf(W[(size_t)(k0 + j) * C + n]);
}

// ---------------------------------------------------------------------------
// Merged transform: Ys = Xb@Ws + bs, Yd = Xb@Wd + bd, outputs packed bf16.
// ---------------------------------------------------------------------------
template <int NT>
__global__ __launch_bounds__(256) void mfma_xform2(
    const unsigned short* __restrict__ Xb,
    const unsigned short* __restrict__ BpS, const unsigned short* __restrict__ BpD,
    const float* __restrict__ bS, const float* __restrict__ bD,
    unsigned int* __restrict__ Ys, unsigned int* __restrict__ Yd, int M) {
  const int wave = threadIdx.x >> 6;
  const int lane = threadIdx.x & 63;
  const int row0 = blockIdx.x * 64 + wave * 16;
  const int m = lane & 15, q = lane >> 4;
  const int arow = min(row0 + m, M - 1);
  const unsigned short* aptr = Xb + (size_t)arow * 128 + q * 8;
  short8v a[4];
#pragma unroll
  for (int kc = 0; kc < 4; kc++) a[kc] = *(const short8v*)(aptr + kc * 32);
  float4v accS[NT], accD[NT];
#pragma unroll
  for (int t = 0; t < NT; t++) { accS[t] = (float4v)(0.f); accD[t] = (float4v)(0.f); }
#pragma unroll
  for (int kc = 0; kc < 4; kc++) {
#pragma unroll
    for (int t = 0; t < NT; t++) {
      short8v bs = *(const short8v*)(BpS + ((size_t)(t * 4 + kc) * 64 + lane) * 8);
      short8v bd = *(const short8v*)(BpD + ((size_t)(t * 4 + kc) * 64 + lane) * 8);
      accS[t] = __builtin_amdgcn_mfma_f32_16x16x32_bf16(a[kc], bs, accS[t], 0, 0, 0);
      accD[t] = __builtin_amdgcn_mfma_f32_16x16x32_bf16(a[kc], bd, accD[t], 0, 0, 0);
    }
  }
  const bool even = (m & 1) == 0;
#pragma unroll
  for (int t = 0; t < NT; t++) {
    const int col = t * 16 + m;
    const float bcS = bS[col], bcD = bD[col];
#pragma unroll
    for (int r = 0; r < 4; r++) {
      const int row = row0 + q * 4 + r;
      float vS = accS[t][r] + bcS;
      float vD = accD[t][r] + bcD;
      float pS = __shfl_xor(vS, 1);
      float pD = __shfl_xor(vD, 1);
      if (even && row < M) {
        size_t idx = (size_t)row * (NT * 8) + t * 8 + (m >> 1);
        Ys[idx] = packbf(vS, pS);
        Yd[idx] = packbf(vD, pD);
      }
    }
  }
}

// ---------------------------------------------------------------------------
// CSR build, two-level counting sort. Buckets of 256 dst values.
// ---------------------------------------------------------------------------
__global__ __launch_bounds__(256) void bucket_hist(
    const int* __restrict__ ei, int* __restrict__ bhist, int N, int E, int NB) {
  __shared__ int cnt[256];
  const int tid = threadIdx.x;
  cnt[tid] = 0;
  __syncthreads();
  const int base = blockIdx.x * 4096;
  const int vn = min(4096, E - base);
#pragma unroll 4
  for (int j = 0; j < 16; j++) {
    int i = j * 256 + tid;
    if (i < vn) {
      int d = ei[E + base + i];
      d = min(max(d, 0), N - 1);
      atomicAdd(&cnt[d >> 8], 1);
    }
  }
  __syncthreads();
  if (tid < NB && cnt[tid]) atomicAdd(&bhist[tid], cnt[tid]);
}

__global__ __launch_bounds__(256) void bucket_scan(
    const int* __restrict__ bhist, int* __restrict__ bbase,
    int* __restrict__ bcur, int NB) {
  __shared__ int ws[8];
  const int tid = threadIdx.x;
  int v = (tid < NB) ? bhist[tid] : 0;
  int excl = block_scan256(v, tid, ws);
  if (tid <= NB) bbase[tid] = excl;
  if (tid < NB) bcur[tid] = excl;
}

__global__ __launch_bounds__(256) void bucket_sort(
    const int* __restrict__ ei, int* __restrict__ bcur,
    unsigned int* __restrict__ pairs, int N, int E, int NB) {
  __shared__ int cnt[256];
  __shared__ int offs[256];
  __shared__ int gbase[256];
  __shared__ int lcur[256];
  __shared__ int ws[8];
  __shared__ unsigned int packed_s[4096];
  __shared__ unsigned char bucket_of[4096];
  const int tid = threadIdx.x;
  cnt[tid] = 0;
  __syncthreads();
  const int base = blockIdx.x * 4096;
  const int vn = min(4096, E - base);
#pragma unroll 4
  for (int j = 0; j < 16; j++) {
    int i = j * 256 + tid;
    if (i < vn) {
      int d = ei[E + base + i];
      d = min(max(d, 0), N - 1);
      atomicAdd(&cnt[d >> 8], 1);
    }
  }
  __syncthreads();
  int excl = block_scan256(cnt[tid], tid, ws);
  offs[tid] = excl;
  lcur[tid] = excl;
  if (tid < NB && cnt[tid]) gbase[tid] = atomicAdd(&bcur[tid], cnt[tid]);
  __syncthreads();
#pragma unroll 4
  for (int j = 0; j < 16; j++) {
    int i = j * 256 + tid;
    if (i < vn) {
      int s = ei[base + i];
      int d = ei[E + base + i];
      s = min(max(s, 0), N - 1);
      d = min(max(d, 0), N - 1);
      int b = d >> 8;
      int slot = atomicAdd(&lcur[b], 1);
      packed_s[slot] = (unsigned)s | ((unsigned)(d & 255) << 16);
      bucket_of[slot] = (unsigned char)b;
    }
  }
  __syncthreads();
  for (int i = tid; i < vn; i += 256) {
    int b = bucket_of[i];
    pairs[gbase[b] + (i - offs[b])] = packed_s[i];
  }
}

__global__ __launch_bounds__(256) void csr_fine(
    const unsigned int* __restrict__ pairs, const int* __restrict__ bbase,
    int* __restrict__ row_ofs, int* __restrict__ src_sorted, int N, int E, int NB) {
  __shared__ int cnt[256];
  __shared__ int cursor[256];
  __shared__ int ws[8];
  const int tid = threadIdx.x;
  const int b = blockIdx.x;
  const int d0 = b << 8;
  const int nd = min(256, N - d0);
  const int pbase = bbase[b];
  const int pcnt = bbase[b + 1] - pbase;
  const int row_base = pbase + d0;
  cnt[tid] = (tid < nd) ? 1 : 0;
  __syncthreads();
  for (int i = tid; i < pcnt; i += 256) {
    unsigned p = pairs[pbase + i];
    atomicAdd(&cnt[(p >> 16) & 255], 1);
  }
  __syncthreads();
  int excl = block_scan256(cnt[tid], tid, ws);
  if (tid < nd) {
    row_ofs[d0 + tid] = row_base + excl;
    src_sorted[row_base + excl] = d0 + tid;
    cursor[tid] = excl + 1;
  }
  if (b == NB - 1 && tid == 0) row_ofs[N] = E + N;
  __syncthreads();
  for (int i = tid; i < pcnt; i += 256) {
    unsigned p = pairs[pbase + i];
    int dl = (p >> 16) & 255;
    int slot = atomicAdd(&cursor[dl], 1);
    src_sorted[row_base + slot] = (int)(p & 0xffffu);
  }
}

// ---------------------------------------------------------------------------
// Layer-1 fused: one wave per dst node, 4 edges/iteration.
// 16 lanes/edge (g = lane>>4), l = lane&15 covers ch 8l..8l+7 (uint4).
// head = l>>1 -> p-reduce = 1 shfl. Cross-group combine xor 16, 32.
// float2 vector math -> packed v_pk_* f32 ops.
// ---------------------------------------------------------------------------
__global__ __launch_bounds__(256) void gat1_fused(
    const int* __restrict__ row_ofs, const int* __restrict__ src_sorted,
    const unsigned int* __restrict__ xsb, const unsigned int* __restrict__ xdb,
    const float* __restrict__ att, const float* __restrict__ bias,
    unsigned int* __restrict__ h1b, int N) {
  const int node = (int)((blockIdx.x * 256u + threadIdx.x) >> 6);
  const int lane = threadIdx.x & 63;
  const int l = lane & 15;
  if (node >= N) return;
  float2v at[4], xd[4];
  {
    const float4 at01 = *(const float4*)(att + 8 * l);
    const float4 at23 = *(const float4*)(att + 8 * l + 4);
    at[0].x = at01.x; at[0].y = at01.y; at[1].x = at01.z; at[1].y = at01.w;
    at[2].x = at23.x; at[2].y = at23.y; at[3].x = at23.z; at[3].y = at23.w;
    const uint4 xdp = *(const uint4*)(xdb + (size_t)node * 64 + 4 * l);
    xd[0] = unpack2(xdp.x); xd[1] = unpack2(xdp.y);
    xd[2] = unpack2(xdp.z); xd[3] = unpack2(xdp.w);
  }
  float2v acc[4];
#pragma unroll
  for (int i = 0; i < 4; i++) acc[i] = (float2v)(0.f);
  float den = 0.f;
  const int b = row_ofs[node], eend = row_ofs[node + 1];
  const int iters = (eend - b + 3) >> 2;
  int e = b + (lane >> 4);
  bool valid = e < eend;
  int s0 = valid ? src_sorted[e] : node;
  uint4 mp = *(const uint4*)(xsb + (size_t)s0 * 64 + 4 * l);
  for (int it = 0; it < iters; it++) {
    const uint4 cur = mp;
    const bool v = valid;
    e += 4;
    valid = e < eend;
    if (it + 1 < iters) {
      int sn = valid ? src_sorted[e] : node;
      mp = *(const uint4*)(xsb + (size_t)sn * 64 + 4 * l);
    }
    float2v m[4];
    m[0] = unpack2(cur.x); m[1] = unpack2(cur.y);
    m[2] = unpack2(cur.z); m[3] = unpack2(cur.w);
    float2v pk = (float2v)(0.f);
#pragma unroll
    for (int i = 0; i < 4; i++) {
      float2v t = m[i] + xd[i];
      float2v lr = __builtin_elementwise_max(t, t * NEG_SLOPE);
      pk += lr * at[i];
    }
    float p = pk.x + pk.y;
    p += __shfl_xor(p, 1);
    float ex = v ? __expf(p) : 0.f;
    den += ex;
    float2v ex2; ex2.x = ex; ex2.y = ex;
#pragma unroll
    for (int i = 0; i < 4; i++) acc[i] += ex2 * m[i];
  }
#pragma unroll
  for (int off = 16; off < 64; off <<= 1) {
#pragma unroll
    for (int i = 0; i < 4; i++) {
      acc[i].x += __shfl_xor(acc[i].x, off);
      acc[i].y += __shfl_xor(acc[i].y, off);
    }
    den += __shfl_xor(den, off);
  }
  if (lane < 16) {
    const float inv = 1.f / den;
    const float4 bc01 = *(const float4*)(bias + 8 * l);
    const float4 bc23 = *(const float4*)(bias + 8 * l + 4);
    float v0 = fmaf(acc[0].x, inv, bc01.x);
    float v1 = fmaf(acc[0].y, inv, bc01.y);
    float v2 = fmaf(acc[1].x, inv, bc01.z);
    float v3 = fmaf(acc[1].y, inv, bc01.w);
    float v4 = fmaf(acc[2].x, inv, bc23.x);
    float v5 = fmaf(acc[2].y, inv, bc23.y);
    float v6 = fmaf(acc[3].x, inv, bc23.z);
    float v7 = fmaf(acc[3].y, inv, bc23.w);
    v0 = v0 > 0.f ? v0 : __expf(v0) - 1.f;
    v1 = v1 > 0.f ? v1 : __expf(v1) - 1.f;
    v2 = v2 > 0.f ? v2 : __expf(v2) - 1.f;
    v3 = v3 > 0.f ? v3 : __expf(v3) - 1.f;
    v4 = v4 > 0.f ? v4 : __expf(v4) - 1.f;
    v5 = v5 > 0.f ? v5 : __expf(v5) - 1.f;
    v6 = v6 > 0.f ? v6 : __expf(v6) - 1.f;
    v7 = v7 > 0.f ? v7 : __expf(v7) - 1.f;
    uint4 o;
    o.x = packbf(v0, v1); o.y = packbf(v2, v3);
    o.z = packbf(v4, v5); o.w = packbf(v6, v7);
    *(uint4*)(h1b + (size_t)node * 64 + 4 * l) = o;
  }
}

// ---------------------------------------------------------------------------
// Layer-2 fused: one wave per dst node, 16 edges/iteration.
// 4 lanes/edge (g = lane>>2), l = lane&3 covers ch 8l..8l+7 (uint4).
// p-reduce = 2 shfl; cross-group combine xor 4..32; + log_softmax.
// ---------------------------------------------------------------------------
__global__ __launch_bounds__(256) void gat2_fused(
    const int* __restrict__ row_ofs, const int* __restrict__ src_sorted,
    const unsigned int* __restrict__ xsb, const unsigned int* __restrict__ xdb,
    const float* __restrict__ att, const float* __restrict__ bias,
    float* __restrict__ out, int N) {
  const int node = (int)((blockIdx.x * 256u + threadIdx.x) >> 6);
  const int lane = threadIdx.x & 63;
  const int l = lane & 3;
  if (node >= N) return;
  float2v at[4], xd[4];
  {
    const float4 at01 = *(const float4*)(att + 8 * l);
    const float4 at23 = *(const float4*)(att + 8 * l + 4);
    at[0].x = at01.x; at[0].y = at01.y; at[1].x = at01.z; at[1].y = at01.w;
    at[2].x = at23.x; at[2].y = at23.y; at[3].x = at23.z; at[3].y = at23.w;
    const uint4 xdp = *(const uint4*)(xdb + (size_t)node * 16 + 4 * l);
    xd[0] = unpack2(xdp.x); xd[1] = unpack2(xdp.y);
    xd[2] = unpack2(xdp.z); xd[3] = unpack2(xdp.w);
  }
  float2v acc[4];
#pragma unroll
  for (int i = 0; i < 4; i++) acc[i] = (float2v)(0.f);
  float den = 0.f;
  const int b = row_ofs[node], eend = row_ofs[node + 1];
  const int iters = (eend - b + 15) >> 4;
  int e = b + (lane >> 2);
  bool valid = e < eend;
  int s0 = valid ? src_sorted[e] : node;
  uint4 mp = *(const uint4*)(xsb + (size_t)s0 * 16 + 4 * l);
  for (int it = 0; it < iters; it++) {
    const uint4 cur = mp;
    const bool v = valid;
    e += 16;
    valid = e < eend;
    if (it + 1 < iters) {
      int sn = valid ? src_sorted[e] : node;
      mp = *(const uint4*)(xsb + (size_t)sn * 16 + 4 * l);
    }
    float2v m[4];
    m[0] = unpack2(cur.x); m[1] = unpack2(cur.y);
    m[2] = unpack2(cur.z); m[3] = unpack2(cur.w);
    float2v pk = (float2v)(0.f);
#pragma unroll
    for (int i = 0; i < 4; i++) {
      float2v t = m[i] + xd[i];
      float2v lr = __builtin_elementwise_max(t, t * NEG_SLOPE);
      pk += lr * at[i];
    }
    float p = pk.x + pk.y;
    p += __shfl_xor(p, 1);
    p += __shfl_xor(p, 2);
    float ex = v ? __expf(p) : 0.f;
    den += ex;
    float2v ex2; ex2.x = ex; ex2.y = ex;
#pragma unroll
    for (int i = 0; i < 4; i++) acc[i] += ex2 * m[i];
  }
#pragma unroll
  for (int off = 4; off < 64; off <<= 1) {
#pragma unroll
    for (int i = 0; i < 4; i++) {
      acc[i].x += __shfl_xor(acc[i].x, off);
      acc[i].y += __shfl_xor(acc[i].y, off);
    }
    den += __shfl_xor(den, off);
  }
  if (lane < 4) {
    const float inv = 1.f / den;
    const float4 bc01 = *(const float4*)(bias + 8 * l);
    const float4 bc23 = *(const float4*)(bias + 8 * l + 4);
    float v0 = fmaf(acc[0].x, inv, bc01.x);
    float v1 = fmaf(acc[0].y, inv, bc01.y);
    float v2 = fmaf(acc[1].x, inv, bc01.z);
    float v3 = fmaf(acc[1].y, inv, bc01.w);
    float v4 = fmaf(acc[2].x, inv, bc23.x);
    float v5 = fmaf(acc[2].y, inv, bc23.y);
    float v6 = fmaf(acc[3].x, inv, bc23.z);
    float v7 = fmaf(acc[3].y, inv, bc23.w);
    // log_softmax over 32 channels (8 local x 4 lanes)
    float mx = fmaxf(fmaxf(fmaxf(v0, v1), fmaxf(v2, v3)),
                     fmaxf(fmaxf(v4, v5), fmaxf(v6, v7)));
    mx = fmaxf(mx, __shfl_xor(mx, 1));
    mx = fmaxf(mx, __shfl_xor(mx, 2));
    float sum = __expf(v0 - mx) + __expf(v1 - mx) + __expf(v2 - mx) +
                __expf(v3 - mx) + __expf(v4 - mx) + __expf(v5 - mx) +
                __expf(v6 - mx) + __expf(v7 - mx);
    sum += __shfl_xor(sum, 1);
    sum += __shfl_xor(sum, 2);
    const float lse = mx + __logf(sum);
    float* op = out + (size_t)node * 32 + 8 * l;
    *(float4*)op = make_float4(v0 - lse, v1 - lse, v2 - lse, v3 - lse);
    *(float4*)(op + 4) = make_float4(v4 - lse, v5 - lse, v6 - lse, v7 - lse);
  }
}

extern "C" void kernel_launch(void* const* d_in, const int* in_sizes, int n_in,
                              void* d_out, int out_size, void* d_ws, size_t ws_size,
                              hipStream_t stream) {
  const float* x = (const float*)d_in[0];
  const int* ei = (const int*)d_in[1];
  const float* W1s = (const float*)d_in[2];
  const float* W1d = (const float*)d_in[3];
  const float* b1s = (const float*)d_in[4];
  const float* b1d = (const float*)d_in[5];
  const float* att1 = (const float*)d_in[6];
  const float* bias1 = (const float*)d_in[7];
  const float* W2s = (const float*)d_in[8];
  const float* W2d = (const float*)d_in[9];
  const float* b2s = (const float*)d_in[10];
  const float* b2d = (const float*)d_in[11];
  const float* att2 = (const float*)d_in[12];
  const float* bias2 = (const float*)d_in[13];
  float* out = (float*)d_out;

  const int N = in_sizes[0] / 128;
  const int E = in_sizes[1] / 2;
  const int NB = (N + 255) >> 8;

  char* p = (char*)d_ws;
  auto alloc = [&](size_t bytes) { char* r = p; p += (bytes + 63) & ~63ull; return r; };
  unsigned int* xs1b = (unsigned int*)alloc((size_t)N * 64 * 4);
  unsigned int* xd1b = (unsigned int*)alloc((size_t)N * 64 * 4);
  unsigned int* xs2b = (unsigned int*)alloc((size_t)N * 16 * 4);
  unsigned int* xd2b = (unsigned int*)alloc((size_t)N * 16 * 4);
  unsigned short* xb = (unsigned short*)alloc((size_t)N * 128 * 2);
  unsigned int* h1b = (unsigned int*)alloc((size_t)N * 64 * 4);
  unsigned short* Bp1s = (unsigned short*)alloc(8 * 4 * 64 * 8 * 2);
  unsigned short* Bp1d = (unsigned short*)alloc(8 * 4 * 64 * 8 * 2);
  unsigned short* Bp2s = (unsigned short*)alloc(2 * 4 * 64 * 8 * 2);
  unsigned short* Bp2d = (unsigned short*)alloc(2 * 4 * 64 * 8 * 2);
  int* bhist = (int*)alloc((size_t)NB * 4);
  int* bbase = (int*)alloc((size_t)(NB + 1) * 4);
  int* bcur = (int*)alloc((size_t)NB * 4);
  unsigned int* pairs = (unsigned int*)alloc((size_t)E * 4);
  int* row_ofs = (int*)alloc((size_t)(N + 1) * 4);
  int* src_sorted = (int*)alloc((size_t)(E + N) * 4);

  hipMemsetAsync(bhist, 0, (size_t)NB * sizeof(int), stream);

  const int total4 = N * 128 / 4;
  cvt_bf16_kernel<<<(total4 + 255) / 256, 256, 0, stream>>>(x, xb, total4);
  pack_all<<<20, 256, 0, stream>>>(W1s, W1d, W2s, W2d, Bp1s, Bp1d, Bp2s, Bp2d);

  const int nA = (E + 4095) / 4096;
  bucket_hist<<<nA, 256, 0, stream>>>(ei, bhist, N, E, NB);
  bucket_scan<<<1, 256, 0, stream>>>(bhist, bbase, bcur, NB);
  bucket_sort<<<nA, 256, 0, stream>>>(ei, bcur, pairs, N, E, NB);
  csr_fine<<<NB, 256, 0, stream>>>(pairs, bbase, row_ofs, src_sorted, N, E, NB);

  const int xblocks = (N + 63) / 64;
  mfma_xform2<8><<<xblocks, 256, 0, stream>>>(xb, Bp1s, Bp1d, b1s, b1d, xs1b, xd1b, N);

  gat1_fused<<<(N + 3) / 4, 256, 0, stream>>>(row_ofs, src_sorted, xs1b, xd1b,
                                              att1, bias1, h1b, N);

  mfma_xform2<2><<<xblocks, 256, 0, stream>>>((const unsigned short*)h1b, Bp2s, Bp2d,
                                              b2s, b2d, xs2b, xd2b, N);

  gat2_fused<<<(N + 3) / 4, 256, 0, stream>>>(row_ofs, src_sorted, xs2b, xd2b,
                                              att2, bias2, out, N);
}

// Round 10
// 232.901 us; speedup vs baseline: 3.4822x; 1.0106x over previous
//
#include <hip/hip_runtime.h>
#include <math.h>

#define NEG_SLOPE 0.2f

typedef __attribute__((ext_vector_type(8))) short short8v;
typedef __attribute__((ext_vector_type(4))) float float4v;
typedef __attribute__((ext_vector_type(2))) float float2v;

__device__ __forceinline__ float lrelu(float x) { return fmaxf(x, NEG_SLOPE * x); }

__device__ __forceinline__ unsigned short f2bf(float f) {
  unsigned u = __float_as_uint(f);
  u += 0x7fffu + ((u >> 16) & 1u);
  return (unsigned short)(u >> 16);
}
__device__ __forceinline__ float bflo(unsigned v) { return __uint_as_float(v << 16); }
__device__ __forceinline__ float bfhi(unsigned v) { return __uint_as_float(v & 0xffff0000u); }
__device__ __forceinline__ unsigned packbf(float a, float b) {
  return (unsigned)f2bf(a) | ((unsigned)f2bf(b) << 16);
}
__device__ __forceinline__ float2v unpack2(unsigned u) {
  float2v r; r.x = bflo(u); r.y = bfhi(u); return r;
}

// 256-wide block exclusive scan; all 256 threads must call. ws: >=8 ints LDS.
__device__ __forceinline__ int block_scan256(int v, int tid, int* ws) {
  const int lane = tid & 63, w = tid >> 6;
  int incl = v;
#pragma unroll
  for (int off = 1; off < 64; off <<= 1) {
    int t = __shfl_up(incl, off);
    if (lane >= off) incl += t;
  }
  if (lane == 63) ws[w] = incl;
  __syncthreads();
  if (tid == 0) {
    int s = 0;
#pragma unroll
    for (int i = 0; i < 4; i++) { int t = ws[i]; ws[4 + i] = s; s += t; }
  }
  __syncthreads();
  return incl - v + ws[4 + w];
}

// ---------------------------------------------------------------------------
// x (fp32) -> bf16, 4 elements per thread
// ---------------------------------------------------------------------------
__global__ __launch_bounds__(256) void cvt_bf16_kernel(
    const float* __restrict__ X, unsigned short* __restrict__ Xb, int total4) {
  int i = blockIdx.x * 256 + threadIdx.x;
  if (i >= total4) return;
  float4 v = ((const float4*)X)[i];
  ushort4 o;
  o.x = f2bf(v.x); o.y = f2bf(v.y); o.z = f2bf(v.z); o.w = f2bf(v.w);
  ((ushort4*)Xb)[i] = o;
}

// ---------------------------------------------------------------------------
// Pack all 4 weight matrices into MFMA B-fragment layout (bf16), one launch.
// ---------------------------------------------------------------------------
__global__ __launch_bounds__(256) void pack_all(
    const float* __restrict__ W1s, const float* __restrict__ W1d,
    const float* __restrict__ W2s, const float* __restrict__ W2d,
    unsigned short* __restrict__ B1s, unsigned short* __restrict__ B1d,
    unsigned short* __restrict__ B2s, unsigned short* __restrict__ B2d) {
  int blk = blockIdx.x;
  const float* W; unsigned short* Bp; int C, base;
  if (blk < 8)       { W = W1s; Bp = B1s; C = 128; base = blk; }
  else if (blk < 16) { W = W1d; Bp = B1d; C = 128; base = blk - 8; }
  else if (blk < 18) { W = W2s; Bp = B2s; C = 32;  base = blk - 16; }
  else               { W = W2d; Bp = B2d; C = 32;  base = blk - 18; }
  int idx = base * 256 + threadIdx.x;
  int total = (C / 16) * 4 * 64;
  if (idx >= total) return;
  int lane = idx & 63;
  int kc = (idx >> 6) & 3;
  int t = idx >> 8;
  int n = t * 16 + (lane & 15);
  int k0 = kc * 32 + (lane >> 4) * 8;
  unsigned short* o = Bp + (size_t)idx * 8;
#pragma unroll
  for (int j = 0; j < 8; j++) o[j] = f2bf(W[(size_t)(k0 + j) * C + n]);
}

// ---------------------------------------------------------------------------
// Merged transform: Ys = Xb@Ws + bs, Yd = Xb@Wd + bd, outputs packed bf16.
// ---------------------------------------------------------------------------
template <int NT>
__global__ __launch_bounds__(256) void mfma_xform2(
    const unsigned short* __restrict__ Xb,
    const unsigned short* __restrict__ BpS, const unsigned short* __restrict__ BpD,
    const float* __restrict__ bS, const float* __restrict__ bD,
    unsigned int* __restrict__ Ys, unsigned int* __restrict__ Yd, int M) {
  const int wave = threadIdx.x >> 6;
  const int lane = threadIdx.x & 63;
  const int row0 = blockIdx.x * 64 + wave * 16;
  const int m = lane & 15, q = lane >> 4;
  const int arow = min(row0 + m, M - 1);
  const unsigned short* aptr = Xb + (size_t)arow * 128 + q * 8;
  short8v a[4];
#pragma unroll
  for (int kc = 0; kc < 4; kc++) a[kc] = *(const short8v*)(aptr + kc * 32);
  float4v accS[NT], accD[NT];
#pragma unroll
  for (int t = 0; t < NT; t++) { accS[t] = (float4v)(0.f); accD[t] = (float4v)(0.f); }
#pragma unroll
  for (int kc = 0; kc < 4; kc++) {
#pragma unroll
    for (int t = 0; t < NT; t++) {
      short8v bs = *(const short8v*)(BpS + ((size_t)(t * 4 + kc) * 64 + lane) * 8);
      short8v bd = *(const short8v*)(BpD + ((size_t)(t * 4 + kc) * 64 + lane) * 8);
      accS[t] = __builtin_amdgcn_mfma_f32_16x16x32_bf16(a[kc], bs, accS[t], 0, 0, 0);
      accD[t] = __builtin_amdgcn_mfma_f32_16x16x32_bf16(a[kc], bd, accD[t], 0, 0, 0);
    }
  }
  const bool even = (m & 1) == 0;
#pragma unroll
  for (int t = 0; t < NT; t++) {
    const int col = t * 16 + m;
    const float bcS = bS[col], bcD = bD[col];
#pragma unroll
    for (int r = 0; r < 4; r++) {
      const int row = row0 + q * 4 + r;
      float vS = accS[t][r] + bcS;
      float vD = accD[t][r] + bcD;
      float pS = __shfl_xor(vS, 1);
      float pD = __shfl_xor(vD, 1);
      if (even && row < M) {
        size_t idx = (size_t)row * (NT * 8) + t * 8 + (m >> 1);
        Ys[idx] = packbf(vS, pS);
        Yd[idx] = packbf(vD, pD);
      }
    }
  }
}

// ---------------------------------------------------------------------------
// CSR build, two-level counting sort. Buckets of 256 dst values.
// ---------------------------------------------------------------------------
__global__ __launch_bounds__(256) void bucket_hist(
    const int* __restrict__ ei, int* __restrict__ bhist, int N, int E, int NB) {
  __shared__ int cnt[256];
  const int tid = threadIdx.x;
  cnt[tid] = 0;
  __syncthreads();
  const int base = blockIdx.x * 4096;
  const int vn = min(4096, E - base);
#pragma unroll 4
  for (int j = 0; j < 16; j++) {
    int i = j * 256 + tid;
    if (i < vn) {
      int d = ei[E + base + i];
      d = min(max(d, 0), N - 1);
      atomicAdd(&cnt[d >> 8], 1);
    }
  }
  __syncthreads();
  if (tid < NB && cnt[tid]) atomicAdd(&bhist[tid], cnt[tid]);
}

__global__ __launch_bounds__(256) void bucket_scan(
    const int* __restrict__ bhist, int* __restrict__ bbase,
    int* __restrict__ bcur, int NB) {
  __shared__ int ws[8];
  const int tid = threadIdx.x;
  int v = (tid < NB) ? bhist[tid] : 0;
  int excl = block_scan256(v, tid, ws);
  if (tid <= NB) bbase[tid] = excl;
  if (tid < NB) bcur[tid] = excl;
}

__global__ __launch_bounds__(256) void bucket_sort(
    const int* __restrict__ ei, int* __restrict__ bcur,
    unsigned int* __restrict__ pairs, int N, int E, int NB) {
  __shared__ int cnt[256];
  __shared__ int offs[256];
  __shared__ int gbase[256];
  __shared__ int lcur[256];
  __shared__ int ws[8];
  __shared__ unsigned int packed_s[4096];
  __shared__ unsigned char bucket_of[4096];
  const int tid = threadIdx.x;
  cnt[tid] = 0;
  __syncthreads();
  const int base = blockIdx.x * 4096;
  const int vn = min(4096, E - base);
#pragma unroll 4
  for (int j = 0; j < 16; j++) {
    int i = j * 256 + tid;
    if (i < vn) {
      int d = ei[E + base + i];
      d = min(max(d, 0), N - 1);
      atomicAdd(&cnt[d >> 8], 1);
    }
  }
  __syncthreads();
  int excl = block_scan256(cnt[tid], tid, ws);
  offs[tid] = excl;
  lcur[tid] = excl;
  if (tid < NB && cnt[tid]) gbase[tid] = atomicAdd(&bcur[tid], cnt[tid]);
  __syncthreads();
#pragma unroll 4
  for (int j = 0; j < 16; j++) {
    int i = j * 256 + tid;
    if (i < vn) {
      int s = ei[base + i];
      int d = ei[E + base + i];
      s = min(max(s, 0), N - 1);
      d = min(max(d, 0), N - 1);
      int b = d >> 8;
      int slot = atomicAdd(&lcur[b], 1);
      packed_s[slot] = (unsigned)s | ((unsigned)(d & 255) << 16);
      bucket_of[slot] = (unsigned char)b;
    }
  }
  __syncthreads();
  for (int i = tid; i < vn; i += 256) {
    int b = bucket_of[i];
    pairs[gbase[b] + (i - offs[b])] = packed_s[i];
  }
}

__global__ __launch_bounds__(256) void csr_fine(
    const unsigned int* __restrict__ pairs, const int* __restrict__ bbase,
    int* __restrict__ row_ofs, int* __restrict__ src_sorted, int N, int E, int NB) {
  __shared__ int cnt[256];
  __shared__ int cursor[256];
  __shared__ int ws[8];
  const int tid = threadIdx.x;
  const int b = blockIdx.x;
  const int d0 = b << 8;
  const int nd = min(256, N - d0);
  const int pbase = bbase[b];
  const int pcnt = bbase[b + 1] - pbase;
  const int row_base = pbase + d0;
  cnt[tid] = (tid < nd) ? 1 : 0;
  __syncthreads();
  for (int i = tid; i < pcnt; i += 256) {
    unsigned p = pairs[pbase + i];
    atomicAdd(&cnt[(p >> 16) & 255], 1);
  }
  __syncthreads();
  int excl = block_scan256(cnt[tid], tid, ws);
  if (tid < nd) {
    row_ofs[d0 + tid] = row_base + excl;
    src_sorted[row_base + excl] = d0 + tid;
    cursor[tid] = excl + 1;
  }
  if (b == NB - 1 && tid == 0) row_ofs[N] = E + N;
  __syncthreads();
  for (int i = tid; i < pcnt; i += 256) {
    unsigned p = pairs[pbase + i];
    int dl = (p >> 16) & 255;
    int slot = atomicAdd(&cursor[dl], 1);
    src_sorted[row_base + slot] = (int)(p & 0xffffu);
  }
}

// ---------------------------------------------------------------------------
// Layer-1 fused: one wave per dst node, 4 edges/iteration.
// 16 lanes/edge (g = lane>>4), l = lane&15 covers ch 8l..8l+7 (uint4).
// Edge indices bulk-preloaded 64 at a time (one coalesced load per node on
// average), broadcast per-iteration via __shfl (ds_bpermute) -> the payload
// gather depends only on a register, no index->payload load chain.
// ---------------------------------------------------------------------------
__global__ __launch_bounds__(256) void gat1_fused(
    const int* __restrict__ row_ofs, const int* __restrict__ src_sorted,
    const unsigned int* __restrict__ xsb, const unsigned int* __restrict__ xdb,
    const float* __restrict__ att, const float* __restrict__ bias,
    unsigned int* __restrict__ h1b, int N) {
  const int node = (int)((blockIdx.x * 256u + threadIdx.x) >> 6);
  const int lane = threadIdx.x & 63;
  const int l = lane & 15;
  const int g = lane >> 4;
  if (node >= N) return;
  float2v at[4], xd[4];
  {
    const float4 at01 = *(const float4*)(att + 8 * l);
    const float4 at23 = *(const float4*)(att + 8 * l + 4);
    at[0].x = at01.x; at[0].y = at01.y; at[1].x = at01.z; at[1].y = at01.w;
    at[2].x = at23.x; at[2].y = at23.y; at[3].x = at23.z; at[3].y = at23.w;
    const uint4 xdp = *(const uint4*)(xdb + (size_t)node * 64 + 4 * l);
    xd[0] = unpack2(xdp.x); xd[1] = unpack2(xdp.y);
    xd[2] = unpack2(xdp.z); xd[3] = unpack2(xdp.w);
  }
  float2v acc[4];
#pragma unroll
  for (int i = 0; i < 4; i++) acc[i] = (float2v)(0.f);
  float den = 0.f;
  const int b = row_ofs[node];
  const int cnt = row_ofs[node + 1] - b;
  for (int base = 0; base < cnt; base += 64) {
    const int rem = cnt - base;
    int sidx = (lane < rem) ? src_sorted[b + base + lane] : node;
    const int nIter = min(16, (rem + 3) >> 2);
    int s = __shfl(sidx, g);
    uint4 mp = *(const uint4*)(xsb + (size_t)s * 64 + 4 * l);
    for (int it = 0; it < nIter; it++) {
      const uint4 cur = mp;
      const bool v = (base + 4 * it + g) < cnt;
      if (it + 1 < nIter) {
        int sn = __shfl(sidx, 4 * (it + 1) + g);
        mp = *(const uint4*)(xsb + (size_t)sn * 64 + 4 * l);
      }
      float2v m[4];
      m[0] = unpack2(cur.x); m[1] = unpack2(cur.y);
      m[2] = unpack2(cur.z); m[3] = unpack2(cur.w);
      float2v pk = (float2v)(0.f);
#pragma unroll
      for (int i = 0; i < 4; i++) {
        float2v t = m[i] + xd[i];
        float2v lr = __builtin_elementwise_max(t, t * NEG_SLOPE);
        pk += lr * at[i];
      }
      float p = pk.x + pk.y;
      p += __shfl_xor(p, 1);
      float ex = v ? __expf(p) : 0.f;
      den += ex;
      float2v ex2; ex2.x = ex; ex2.y = ex;
#pragma unroll
      for (int i = 0; i < 4; i++) acc[i] += ex2 * m[i];
    }
  }
#pragma unroll
  for (int off = 16; off < 64; off <<= 1) {
#pragma unroll
    for (int i = 0; i < 4; i++) {
      acc[i].x += __shfl_xor(acc[i].x, off);
      acc[i].y += __shfl_xor(acc[i].y, off);
    }
    den += __shfl_xor(den, off);
  }
  if (lane < 16) {
    const float inv = 1.f / den;
    const float4 bc01 = *(const float4*)(bias + 8 * l);
    const float4 bc23 = *(const float4*)(bias + 8 * l + 4);
    float v0 = fmaf(acc[0].x, inv, bc01.x);
    float v1 = fmaf(acc[0].y, inv, bc01.y);
    float v2 = fmaf(acc[1].x, inv, bc01.z);
    float v3 = fmaf(acc[1].y, inv, bc01.w);
    float v4 = fmaf(acc[2].x, inv, bc23.x);
    float v5 = fmaf(acc[2].y, inv, bc23.y);
    float v6 = fmaf(acc[3].x, inv, bc23.z);
    float v7 = fmaf(acc[3].y, inv, bc23.w);
    v0 = v0 > 0.f ? v0 : __expf(v0) - 1.f;
    v1 = v1 > 0.f ? v1 : __expf(v1) - 1.f;
    v2 = v2 > 0.f ? v2 : __expf(v2) - 1.f;
    v3 = v3 > 0.f ? v3 : __expf(v3) - 1.f;
    v4 = v4 > 0.f ? v4 : __expf(v4) - 1.f;
    v5 = v5 > 0.f ? v5 : __expf(v5) - 1.f;
    v6 = v6 > 0.f ? v6 : __expf(v6) - 1.f;
    v7 = v7 > 0.f ? v7 : __expf(v7) - 1.f;
    uint4 o;
    o.x = packbf(v0, v1); o.y = packbf(v2, v3);
    o.z = packbf(v4, v5); o.w = packbf(v6, v7);
    *(uint4*)(h1b + (size_t)node * 64 + 4 * l) = o;
  }
}

// ---------------------------------------------------------------------------
// Layer-2 fused: one wave per dst node, 16 edges/iteration.
// 4 lanes/edge (g = lane>>2), l = lane&3 covers ch 8l..8l+7 (uint4).
// Same bulk index preload + shfl broadcast. + log_softmax epilogue.
// ---------------------------------------------------------------------------
__global__ __launch_bounds__(256) void gat2_fused(
    const int* __restrict__ row_ofs, const int* __restrict__ src_sorted,
    const unsigned int* __restrict__ xsb, const unsigned int* __restrict__ xdb,
    const float* __restrict__ att, const float* __restrict__ bias,
    float* __restrict__ out, int N) {
  const int node = (int)((blockIdx.x * 256u + threadIdx.x) >> 6);
  const int lane = threadIdx.x & 63;
  const int l = lane & 3;
  const int g = lane >> 2;
  if (node >= N) return;
  float2v at[4], xd[4];
  {
    const float4 at01 = *(const float4*)(att + 8 * l);
    const float4 at23 = *(const float4*)(att + 8 * l + 4);
    at[0].x = at01.x; at[0].y = at01.y; at[1].x = at01.z; at[1].y = at01.w;
    at[2].x = at23.x; at[2].y = at23.y; at[3].x = at23.z; at[3].y = at23.w;
    const uint4 xdp = *(const uint4*)(xdb + (size_t)node * 16 + 4 * l);
    xd[0] = unpack2(xdp.x); xd[1] = unpack2(xdp.y);
    xd[2] = unpack2(xdp.z); xd[3] = unpack2(xdp.w);
  }
  float2v acc[4];
#pragma unroll
  for (int i = 0; i < 4; i++) acc[i] = (float2v)(0.f);
  float den = 0.f;
  const int b = row_ofs[node];
  const int cnt = row_ofs[node + 1] - b;
  for (int base = 0; base < cnt; base += 64) {
    const int rem = cnt - base;
    int sidx = (lane < rem) ? src_sorted[b + base + lane] : node;
    const int nIter = min(4, (rem + 15) >> 4);
    int s = __shfl(sidx, g);
    uint4 mp = *(const uint4*)(xsb + (size_t)s * 16 + 4 * l);
    for (int it = 0; it < nIter; it++) {
      const uint4 cur = mp;
      const bool v = (base + 16 * it + g) < cnt;
      if (it + 1 < nIter) {
        int sn = __shfl(sidx, 16 * (it + 1) + g);
        mp = *(const uint4*)(xsb + (size_t)sn * 16 + 4 * l);
      }
      float2v m[4];
      m[0] = unpack2(cur.x); m[1] = unpack2(cur.y);
      m[2] = unpack2(cur.z); m[3] = unpack2(cur.w);
      float2v pk = (float2v)(0.f);
#pragma unroll
      for (int i = 0; i < 4; i++) {
        float2v t = m[i] + xd[i];
        float2v lr = __builtin_elementwise_max(t, t * NEG_SLOPE);
        pk += lr * at[i];
      }
      float p = pk.x + pk.y;
      p += __shfl_xor(p, 1);
      p += __shfl_xor(p, 2);
      float ex = v ? __expf(p) : 0.f;
      den += ex;
      float2v ex2; ex2.x = ex; ex2.y = ex;
#pragma unroll
      for (int i = 0; i < 4; i++) acc[i] += ex2 * m[i];
    }
  }
#pragma unroll
  for (int off = 4; off < 64; off <<= 1) {
#pragma unroll
    for (int i = 0; i < 4; i++) {
      acc[i].x += __shfl_xor(acc[i].x, off);
      acc[i].y += __shfl_xor(acc[i].y, off);
    }
    den += __shfl_xor(den, off);
  }
  if (lane < 4) {
    const float inv = 1.f / den;
    const float4 bc01 = *(const float4*)(bias + 8 * l);
    const float4 bc23 = *(const float4*)(bias + 8 * l + 4);
    float v0 = fmaf(acc[0].x, inv, bc01.x);
    float v1 = fmaf(acc[0].y, inv, bc01.y);
    float v2 = fmaf(acc[1].x, inv, bc01.z);
    float v3 = fmaf(acc[1].y, inv, bc01.w);
    float v4 = fmaf(acc[2].x, inv, bc23.x);
    float v5 = fmaf(acc[2].y, inv, bc23.y);
    float v6 = fmaf(acc[3].x, inv, bc23.z);
    float v7 = fmaf(acc[3].y, inv, bc23.w);
    float mx = fmaxf(fmaxf(fmaxf(v0, v1), fmaxf(v2, v3)),
                     fmaxf(fmaxf(v4, v5), fmaxf(v6, v7)));
    mx = fmaxf(mx, __shfl_xor(mx, 1));
    mx = fmaxf(mx, __shfl_xor(mx, 2));
    float sum = __expf(v0 - mx) + __expf(v1 - mx) + __expf(v2 - mx) +
                __expf(v3 - mx) + __expf(v4 - mx) + __expf(v5 - mx) +
                __expf(v6 - mx) + __expf(v7 - mx);
    sum += __shfl_xor(sum, 1);
    sum += __shfl_xor(sum, 2);
    const float lse = mx + __logf(sum);
    float* op = out + (size_t)node * 32 + 8 * l;
    *(float4*)op = make_float4(v0 - lse, v1 - lse, v2 - lse, v3 - lse);
    *(float4*)(op + 4) = make_float4(v4 - lse, v5 - lse, v6 - lse, v7 - lse);
  }
}

extern "C" void kernel_launch(void* const* d_in, const int* in_sizes, int n_in,
                              void* d_out, int out_size, void* d_ws, size_t ws_size,
                              hipStream_t stream) {
  const float* x = (const float*)d_in[0];
  const int* ei = (const int*)d_in[1];
  const float* W1s = (const float*)d_in[2];
  const float* W1d = (const float*)d_in[3];
  const float* b1s = (const float*)d_in[4];
  const float* b1d = (const float*)d_in[5];
  const float* att1 = (const float*)d_in[6];
  const float* bias1 = (const float*)d_in[7];
  const float* W2s = (const float*)d_in[8];
  const float* W2d = (const float*)d_in[9];
  const float* b2s = (const float*)d_in[10];
  const float* b2d = (const float*)d_in[11];
  const float* att2 = (const float*)d_in[12];
  const float* bias2 = (const float*)d_in[13];
  float* out = (float*)d_out;

  const int N = in_sizes[0] / 128;
  const int E = in_sizes[1] / 2;
  const int NB = (N + 255) >> 8;

  char* p = (char*)d_ws;
  auto alloc = [&](size_t bytes) { char* r = p; p += (bytes + 63) & ~63ull; return r; };
  unsigned int* xs1b = (unsigned int*)alloc((size_t)N * 64 * 4);
  unsigned int* xd1b = (unsigned int*)alloc((size_t)N * 64 * 4);
  unsigned int* xs2b = (unsigned int*)alloc((size_t)N * 16 * 4);
  unsigned int* xd2b = (unsigned int*)alloc((size_t)N * 16 * 4);
  unsigned short* xb = (unsigned short*)alloc((size_t)N * 128 * 2);
  unsigned int* h1b = (unsigned int*)alloc((size_t)N * 64 * 4);
  unsigned short* Bp1s = (unsigned short*)alloc(8 * 4 * 64 * 8 * 2);
  unsigned short* Bp1d = (unsigned short*)alloc(8 * 4 * 64 * 8 * 2);
  unsigned short* Bp2s = (unsigned short*)alloc(2 * 4 * 64 * 8 * 2);
  unsigned short* Bp2d = (unsigned short*)alloc(2 * 4 * 64 * 8 * 2);
  int* bhist = (int*)alloc((size_t)NB * 4);
  int* bbase = (int*)alloc((size_t)(NB + 1) * 4);
  int* bcur = (int*)alloc((size_t)NB * 4);
  unsigned int* pairs = (unsigned int*)alloc((size_t)E * 4);
  int* row_ofs = (int*)alloc((size_t)(N + 1) * 4);
  int* src_sorted = (int*)alloc((size_t)(E + N) * 4);

  hipMemsetAsync(bhist, 0, (size_t)NB * sizeof(int), stream);

  const int total4 = N * 128 / 4;
  cvt_bf16_kernel<<<(total4 + 255) / 256, 256, 0, stream>>>(x, xb, total4);
  pack_all<<<20, 256, 0, stream>>>(W1s, W1d, W2s, W2d, Bp1s, Bp1d, Bp2s, Bp2d);

  const int nA = (E + 4095) / 4096;
  bucket_hist<<<nA, 256, 0, stream>>>(ei, bhist, N, E, NB);
  bucket_scan<<<1, 256, 0, stream>>>(bhist, bbase, bcur, NB);
  bucket_sort<<<nA, 256, 0, stream>>>(ei, bcur, pairs, N, E, NB);
  csr_fine<<<NB, 256, 0, stream>>>(pairs, bbase, row_ofs, src_sorted, N, E, NB);

  const int xblocks = (N + 63) / 64;
  mfma_xform2<8><<<xblocks, 256, 0, stream>>>(xb, Bp1s, Bp1d, b1s, b1d, xs1b, xd1b, N);

  gat1_fused<<<(N + 3) / 4, 256, 0, stream>>>(row_ofs, src_sorted, xs1b, xd1b,
                                              att1, bias1, h1b, N);

  mfma_xform2<2><<<xblocks, 256, 0, stream>>>((const unsigned short*)h1b, Bp2s, Bp2d,
                                              b2s, b2d, xs2b, xd2b, N);

  gat2_fused<<<(N + 3) / 4, 256, 0, stream>>>(row_ofs, src_sorted, xs2b, xd2b,
                                              att2, bias2, out, N);
}